// Round 14
// baseline (535.406 us; speedup 1.0000x reference)
//
#include <hip/hip_runtime.h>
#include <hip/hip_bf16.h>

typedef __attribute__((ext_vector_type(8))) short bf16x8;
typedef __attribute__((ext_vector_type(4))) float f32x4;
typedef __attribute__((ext_vector_type(4))) unsigned short u16x4;
typedef unsigned short u16;
typedef unsigned int u32;

#define BSZ 16
#define RO 10752000
#define AO 11289600
#define SO 11306400

__device__ __forceinline__ float sigm(float x) { return 1.f / (1.f + __expf(-x)); }

__device__ __forceinline__ u16 f2bf(float f) {
  u32 u = __float_as_uint(f);
  u = u + 0x7FFF + ((u >> 16) & 1);
  return (u16)(u >> 16);
}
__device__ __forceinline__ float bf2f(u16 v) { return __uint_as_float(((u32)v) << 16); }

__device__ __forceinline__ void gll16(const void* g, void* l) {
  __builtin_amdgcn_global_load_lds((const __attribute__((address_space(1))) void*)g,
                                   (__attribute__((address_space(3))) void*)l, 16, 0, 0);
}

// bijective XCD-chunked swizzle (m204) — apply only within cost-uniform segments
__device__ __forceinline__ int xswz(int bid, int n) {
  int q = n >> 3, r = n & 7;
  int x = bid & 7, i = bid >> 3;
  return (x < r ? x * (q + 1) : r * (q + 1) + (x - r) * q) + i;
}

// ---------------- anchors ----------------
__global__ __launch_bounds__(256) void k_anchor(float* out) {
  int g = blockIdx.x * 256 + threadIdx.x;
  if (g >= 8400) return;
  int l = g < 400 ? 0 : (g < 2000 ? 1 : 2);
  int off = l == 0 ? 0 : (l == 1 ? 400 : 2000);
  int w = 20 << l;
  float s = (float)(32 >> l);
  int p = g - off;
  int x = p % w, y = p / w;
  out[AO + 2 * g] = x + 0.5f;
  out[AO + 2 * g + 1] = y + 0.5f;
  out[SO + g] = s;
}

// ---------------- featT prep + fused avg partial sums ----------------
struct PFArgs { const float* feat[3]; u16* fT[3]; float* avg; };

__global__ __launch_bounds__(256) void k_prepF2(PFArgs A, int s1, int s2) {
  __shared__ float buf[32][65];
  int bid = blockIdx.x;
  int l = bid >= s2 ? 2 : (bid >= s1 ? 1 : 0);
  int loc = bid - (l == 2 ? s2 : (l == 1 ? s1 : 0));
  int C = 768 >> l, HW = 400 << (2 * l);
  int PT = (HW + 63) / 64;
  int pt = loc % PT, b = loc / PT;
  int p0 = pt * 64;
  int tid = threadIdx.x;
  int cc = tid >> 6, pp = tid & 63;
  int pload = p0 + pp;
  bool lok = pload < HW;
  int plc = lok ? pload : 0;
  int pw = tid >> 2, cg = (tid & 3) * 8;
  bool wok = p0 + pw < HW;
  int rch = tid >> 3, rgp = tid & 7;
  const float* src = A.feat[l] + (size_t)b * C * HW;
  u16* dst = A.fT[l] + (size_t)b * HW * C;
  float* avgb = A.avg + (l * BSZ + b) * 768;
  for (int c0 = 0; c0 < C; c0 += 32) {
#pragma unroll
    for (int j = 0; j < 8; j++) {
      int c = c0 + cc * 8 + j;
      float v = src[(size_t)c * HW + plc];
      buf[cc * 8 + j][pp] = lok ? v : 0.f;
    }
    __syncthreads();
    if (wok) {
      bf16x8 h;
#pragma unroll
      for (int j = 0; j < 8; j++) h[j] = (short)f2bf(buf[cg + j][pw]);
      *(bf16x8*)(dst + (size_t)(p0 + pw) * C + c0 + cg) = h;
    }
    {
      float v = 0.f;
#pragma unroll
      for (int k = 0; k < 8; k++) v += buf[rch][rgp * 8 + k];
      v += __shfl_xor(v, 1);
      v += __shfl_xor(v, 2);
      v += __shfl_xor(v, 4);
      if (rgp == 0) atomicAdd(avgb + c0 + rch, v);
    }
    __syncthreads();
  }
}

// ---------------- gates (avg holds raw sums; fold 1/HW here) ----------------
struct GArgs {
  const float *cfw[3], *cfb[3], *rfw[3], *rfb[3];
  float *avg, *gc, *gr;
};

__global__ __launch_bounds__(256) void k_gate(GArgs A, int s1, int s2) {
  int bid = blockIdx.x;
  int l = bid >= s2 ? 2 : (bid >= s1 ? 1 : 0);
  int loc = bid - (l == 2 ? s2 : (l == 1 ? s1 : 0));
  int C = 768 >> l, HW = 400 << (2 * l);
  float inv = 1.f / (float)HW;
  int co = loc % C, b = loc / C;
  const float* av = A.avg + (l * BSZ + b) * 768;
  float sc = 0.f, sr = 0.f;
  for (int ci = threadIdx.x; ci < C; ci += 256) {
    float v = av[ci];
    sc += A.cfw[l][(size_t)co * C + ci] * v;
    sr += A.rfw[l][(size_t)co * C + ci] * v;
  }
  __shared__ float rc[256], rr[256];
  rc[threadIdx.x] = sc; rr[threadIdx.x] = sr;
  __syncthreads();
  for (int o = 128; o > 0; o >>= 1) {
    if (threadIdx.x < o) { rc[threadIdx.x] += rc[threadIdx.x + o]; rr[threadIdx.x] += rr[threadIdx.x + o]; }
    __syncthreads();
  }
  if (threadIdx.x == 0) {
    A.gc[(l * BSZ + b) * 768 + co] = sigm(rc[0] * inv + A.cfb[l][co]);
    A.gr[(l * BSZ + b) * 768 + co] = sigm(rr[0] * inv + A.rfb[l][co]);
  }
}

// ---------------- gated-weight prep ----------------
struct GWArgs {
  const float *w0[3], *w1[3];
  const float *gc, *gr;
  u16 *gwc, *gwr;
  long goff[3];
};

__global__ __launch_bounds__(256) void k_wgate(GWArgs A, int s1, int s2) {
  int bid = blockIdx.x;
  int l = bid >= s2 ? 2 : (bid >= s1 ? 1 : 0);
  int loc = bid - (l == 2 ? s2 : (l == 1 ? s1 : 0));
  int C = 768 >> l;
  int per_b = (C * C) >> 11;
  int tile = loc % per_b, b = loc / per_b;
  int idx = (tile << 11) + threadIdx.x * 8;
  int co = idx / C, ci = idx - co * C;
  const float* g0 = A.gc + (l * BSZ + b) * 768 + ci;
  const float* g1 = A.gr + (l * BSZ + b) * 768 + ci;
  const float* w0 = A.w0[l] + idx;
  const float* w1 = A.w1[l] + idx;
  f32x4 wa0 = *(const f32x4*)(w0), wb0 = *(const f32x4*)(w0 + 4);
  f32x4 wa1 = *(const f32x4*)(w1), wb1 = *(const f32x4*)(w1 + 4);
  f32x4 ga = *(const f32x4*)(g0), gb = *(const f32x4*)(g0 + 4);
  f32x4 ra = *(const f32x4*)(g1), rb = *(const f32x4*)(g1 + 4);
  bf16x8 h0, h1;
#pragma unroll
  for (int j = 0; j < 4; j++) {
    h0[j] = (short)f2bf(wa0[j] * ga[j]);
    h0[j + 4] = (short)f2bf(wb0[j] * gb[j]);
    h1[j] = (short)f2bf(wa1[j] * ra[j]);
    h1[j + 4] = (short)f2bf(wb1[j] * rb[j]);
  }
  size_t o = A.goff[l] + (size_t)b * C * C + idx;
  *(bf16x8*)(A.gwc + o) = h0;
  *(bf16x8*)(A.gwr + o) = h1;
}

// ---------------- weight pre-transpose for conv3 ----------------
__global__ __launch_bounds__(256) void k_wprep(const float* w, u16* dst, int C) {
  int id = blockIdx.x * 256 + threadIdx.x;
  int co = id / C, ci = id - co * C;
  const float* s = w + (size_t)id * 9;
#pragma unroll
  for (int t = 0; t < 9; t++) dst[((size_t)(t * 96 + co)) * C + ci] = f2bf(s[t]);
}

// ---------------- conv1p: dual-branch 1x1 GEMM, counted vmcnt + per-level XCD swizzle ----------------
struct C1WLvl {
  const u16 *gwc, *gwr;
  const float *b0, *b1;
  const u16* fT;
  u16 *tcT, *trT;
  int C, HW, ntiles, mblks, bstart, cnt;
};
struct C1WArgs { C1WLvl l[3]; };

__global__ __launch_bounds__(256) void k_conv1p(C1WArgs A) {
  __shared__ char smem[65536];  // 2 buffers x (A0 8K | A1 8K | B 16K)
  int bid = blockIdx.x;
  int li = (bid >= A.l[2].bstart) ? 2 : (bid >= A.l[1].bstart ? 1 : 0);
  const C1WLvl& L = A.l[li];
  int loc = xswz(bid - L.bstart, L.cnt);
  int mb = loc % L.mblks;
  int t2 = loc / L.mblks;
  int nt = t2 % L.ntiles;
  int b = t2 / L.ntiles;
  const int C = L.C, HW = L.HW;
  int p0 = nt * 128, co0 = mb * 64;
  int tid = threadIdx.x, lane = tid & 63, w = tid >> 6;
  int wm = w >> 1, wn = w & 1;
  const u16* fTb = L.fT + (size_t)b * HW * C;
  const u16* gw0 = L.gwc + (size_t)b * C * C;
  const u16* gw1 = L.gwr + (size_t)b * C * C;
  int sl8 = lane & 7;

  const u16* bsrc[4];
#pragma unroll
  for (int i = 0; i < 4; i++) {
    int r = w * 32 + i * 8 + (lane >> 3);
    int p = p0 + r;
    if (p >= HW) p = HW - 1;
    bsrc[i] = fTb + (size_t)p * C + ((sl8 ^ (r & 7)) << 3);
  }
  const u16 *a0src[2], *a1src[2];
#pragma unroll
  for (int i = 0; i < 2; i++) {
    int r = w * 16 + i * 8 + (lane >> 3);
    a0src[i] = gw0 + (size_t)(co0 + r) * C + ((sl8 ^ (r & 7)) << 3);
    a1src[i] = gw1 + (size_t)(co0 + r) * C + ((sl8 ^ (r & 7)) << 3);
  }
  int aoff[2][2], boff[2][4];
#pragma unroll
  for (int ks = 0; ks < 2; ks++) {
    int sl = ks * 4 + (lane >> 4);
#pragma unroll
    for (int mi = 0; mi < 2; mi++) {
      int ar = wm * 32 + mi * 16 + (lane & 15);
      aoff[ks][mi] = ar * 128 + ((sl ^ (ar & 7)) << 4);
    }
#pragma unroll
    for (int ni = 0; ni < 4; ni++) {
      int br = wn * 64 + ni * 16 + (lane & 15);
      boff[ks][ni] = br * 128 + ((sl ^ (br & 7)) << 4);
    }
  }

  f32x4 acc0[2][4], acc1[2][4];
#pragma unroll
  for (int mi = 0; mi < 2; mi++)
#pragma unroll
    for (int ni = 0; ni < 4; ni++) { acc0[mi][ni] = (f32x4){0.f,0.f,0.f,0.f}; acc1[mi][ni] = (f32x4){0.f,0.f,0.f,0.f}; }

  const int nchunk = C >> 6;
  {
    char* buf = smem;
#pragma unroll
    for (int i = 0; i < 4; i++) gll16(bsrc[i], buf + 16384 + (w * 32 + i * 8) * 128);
#pragma unroll
    for (int i = 0; i < 2; i++) {
      gll16(a0src[i], buf + (w * 16 + i * 8) * 128);
      gll16(a1src[i], buf + 8192 + (w * 16 + i * 8) * 128);
    }
  }

  int cur = 0;
  for (int c = 0; c < nchunk; c++) {
    if (c + 1 < nchunk) {
      int cb = (c + 1) << 6;
      char* buf = smem + ((cur ^ 1) << 15);
#pragma unroll
      for (int i = 0; i < 4; i++) gll16(bsrc[i] + cb, buf + 16384 + (w * 32 + i * 8) * 128);
#pragma unroll
      for (int i = 0; i < 2; i++) {
        gll16(a0src[i] + cb, buf + (w * 16 + i * 8) * 128);
        gll16(a1src[i] + cb, buf + 8192 + (w * 16 + i * 8) * 128);
      }
      asm volatile("s_waitcnt vmcnt(8)" ::: "memory");
    } else {
      asm volatile("s_waitcnt vmcnt(0)" ::: "memory");
    }
    __builtin_amdgcn_sched_barrier(0);
    __builtin_amdgcn_s_barrier();
    __builtin_amdgcn_sched_barrier(0);

    char* B0 = smem + (cur << 15);
#pragma unroll
    for (int ks = 0; ks < 2; ks++) {
      bf16x8 a0[2], a1[2], bf[4];
#pragma unroll
      for (int mi = 0; mi < 2; mi++) {
        a0[mi] = *(const bf16x8*)(B0 + aoff[ks][mi]);
        a1[mi] = *(const bf16x8*)(B0 + 8192 + aoff[ks][mi]);
      }
#pragma unroll
      for (int ni = 0; ni < 4; ni++) bf[ni] = *(const bf16x8*)(B0 + 16384 + boff[ks][ni]);
#pragma unroll
      for (int mi = 0; mi < 2; mi++)
#pragma unroll
        for (int ni = 0; ni < 4; ni++) {
          acc0[mi][ni] = __builtin_amdgcn_mfma_f32_16x16x32_bf16(a0[mi], bf[ni], acc0[mi][ni], 0, 0, 0);
          acc1[mi][ni] = __builtin_amdgcn_mfma_f32_16x16x32_bf16(a1[mi], bf[ni], acc1[mi][ni], 0, 0, 0);
        }
    }
    __builtin_amdgcn_sched_barrier(0);
    __builtin_amdgcn_s_barrier();
    __builtin_amdgcn_sched_barrier(0);
    cur ^= 1;
  }

#pragma unroll
  for (int mi = 0; mi < 2; mi++) {
    int cob = co0 + wm * 32 + mi * 16 + ((lane >> 4) << 2);
    f32x4 bia0 = *(const f32x4*)(L.b0 + cob);
    f32x4 bia1 = *(const f32x4*)(L.b1 + cob);
#pragma unroll
    for (int ni = 0; ni < 4; ni++) {
      int p = p0 + wn * 64 + ni * 16 + (lane & 15);
      if (p >= HW) continue;
      u16x4 res = *(const u16x4*)(fTb + (size_t)p * C + cob);
      u16x4 o0, o1;
#pragma unroll
      for (int j = 0; j < 4; j++) {
        float x0 = acc0[mi][ni][j] + bia0[j];
        o0[j] = f2bf(x0 * sigm(x0) + bf2f(res[j]));
        float x1 = acc1[mi][ni][j] + bia1[j];
        o1[j] = f2bf(x1 * sigm(x1));
      }
      size_t off = ((size_t)b * HW + p) * C + cob;
      *(u16x4*)(L.tcT + off) = o0;
      *(u16x4*)(L.trT + off) = o1;
    }
  }
}

// ---------------- conv3m: A-operand direct global->reg (L2-hot), B-only LDS dbuf ----------------
struct C3Lvl {
  const u16* inT;
  const u16* wT;
  const float* bias;
  int C, W, H, HW, ntiles, bstart, pos_off;
};
struct C3MArgs { C3Lvl lc[3]; C3Lvl lr[3]; const u16* zp; float* out; int half; };

__global__ __launch_bounds__(256) void k_conv3m(C3MArgs A) {
  __shared__ char smem[34816];  // 2 x B 16K; reg epilogue P[128][68] f32 = 34816
  int rb = blockIdx.x;
  bool isReg = rb >= A.half;
  int bid = isReg ? rb - A.half : rb;
  const C3Lvl* lv = isReg ? A.lr : A.lc;
  int li = (bid >= lv[2].bstart) ? 2 : (bid >= lv[1].bstart ? 1 : 0);
  const C3Lvl& L = lv[li];
  int loc = bid - L.bstart;
  int nt = loc % L.ntiles;
  int b = loc / L.ntiles;
  const int C = L.C, W = L.W, H = L.H, HW = L.HW;
  int p0 = nt * 128;
  int tid = threadIdx.x, lane = tid & 63, w = tid >> 6;
  int wm = w >> 1, wn = w & 1;
  int sl8 = lane & 7;
  const u16* inb = L.inT + (size_t)b * HW * C;
  const u16* wA = L.wT;

  int px[4], py[4];
  bool pv[4];
  const u16* bbase[4];
#pragma unroll
  for (int i = 0; i < 4; i++) {
    int r = w * 32 + i * 8 + (lane >> 3);
    int p = p0 + r;
    pv[i] = p < HW;
    int pp = pv[i] ? p : 0;
    px[i] = pp % W;
    py[i] = pp / W;
    bbase[i] = inb + (size_t)pp * C + ((sl8 ^ (r & 7)) << 3);
  }
  // A-fragment per-lane global row/k offsets (frag: row=lane&15, k=ks*32+(lane>>4)*8)
  int arow[3];
#pragma unroll
  for (int mi = 0; mi < 3; mi++) arow[mi] = wm * 48 + mi * 16 + (lane & 15);
  int akof = (lane >> 4) << 3;

  int boff[2][4];
#pragma unroll
  for (int ks = 0; ks < 2; ks++) {
    int sl = ks * 4 + (lane >> 4);
#pragma unroll
    for (int ni = 0; ni < 4; ni++) {
      int br = wn * 64 + ni * 16 + (lane & 15);
      boff[ks][ni] = br * 128 + ((sl ^ (br & 7)) << 4);
    }
  }

  f32x4 acc[3][4];
#pragma unroll
  for (int mi = 0; mi < 3; mi++)
#pragma unroll
    for (int ni = 0; ni < 4; ni++) acc[mi][ni] = (f32x4){0.f,0.f,0.f,0.f};

  const int nchunk = C >> 6;
  const int total = 9 * nchunk;

  auto STAGEB = [&](int t, int cb, char* buf) {
    int dy = t / 3 - 1, dx = t - (t / 3) * 3 - 1;
    long shift = (long)(dy * W + dx) * C;
#pragma unroll
    for (int i = 0; i < 4; i++) {
      int xx = px[i] + dx, yy = py[i] + dy;
      bool ok = pv[i] && ((unsigned)xx < (unsigned)W) && ((unsigned)yy < (unsigned)H);
      const void* src = ok ? (const void*)(bbase[i] + shift + cb) : (const void*)A.zp;
      gll16(src, buf + (w * 32 + i * 8) * 128);
    }
  };
  auto LOADA = [&](bf16x8 (&dst)[6], int tt, int cb) {
#pragma unroll
    for (int ks = 0; ks < 2; ks++)
#pragma unroll
      for (int mi = 0; mi < 3; mi++)
        dst[ks * 3 + mi] = *(const bf16x8*)(wA + (size_t)(tt * 96 + arow[mi]) * C + cb + ks * 32 + akof);
  };

  bf16x8 aA[6], aB[6];
  STAGEB(0, 0, smem);
  LOADA(aA, 0, 0);

  int cur = 0, t = 0, c = 0;
  auto STEP = [&](bf16x8 (&use)[6], bf16x8 (&pre)[6], int s) {
    int tn = t + 1, cn = c;
    if (tn == 9) { tn = 0; cn = c + 1; }
    if (s + 1 < total) {
      STAGEB(tn, cn << 6, smem + ((cur ^ 1) << 14));
      LOADA(pre, tn, cn << 6);
      __builtin_amdgcn_sched_barrier(0);
      asm volatile("s_waitcnt vmcnt(10)" ::: "memory");
    } else {
      asm volatile("s_waitcnt vmcnt(0)" ::: "memory");
    }
    __builtin_amdgcn_sched_barrier(0);
    __builtin_amdgcn_s_barrier();
    __builtin_amdgcn_sched_barrier(0);
    char* B0 = smem + (cur << 14);
#pragma unroll
    for (int ks = 0; ks < 2; ks++) {
      bf16x8 bf[4];
#pragma unroll
      for (int ni = 0; ni < 4; ni++) bf[ni] = *(const bf16x8*)(B0 + boff[ks][ni]);
#pragma unroll
      for (int mi = 0; mi < 3; mi++)
#pragma unroll
        for (int ni = 0; ni < 4; ni++)
          acc[mi][ni] = __builtin_amdgcn_mfma_f32_16x16x32_bf16(use[ks * 3 + mi], bf[ni], acc[mi][ni], 0, 0, 0);
    }
    __builtin_amdgcn_sched_barrier(0);
    __builtin_amdgcn_s_barrier();
    __builtin_amdgcn_sched_barrier(0);
    cur ^= 1; t = tn; c = cn;
  };

  int s = 0;
  while (true) {
    STEP(aA, aB, s); if (++s == total) break;
    STEP(aB, aA, s); if (++s == total) break;
  }

  if (!isReg) {
#pragma unroll
    for (int mi = 0; mi < 3; mi++) {
      int cob = wm * 48 + mi * 16 + ((lane >> 4) << 2);
      if (cob >= 80) continue;
      f32x4 bia = *(const f32x4*)(L.bias + cob);
#pragma unroll
      for (int ni = 0; ni < 4; ni++) {
        int p = p0 + wn * 64 + ni * 16 + (lane & 15);
        if (p >= HW) continue;
#pragma unroll
        for (int j = 0; j < 4; j++)
          A.out[(size_t)(b * 80 + cob + j) * 8400 + L.pos_off + p] = sigm(acc[mi][ni][j] + bia[j]);
      }
    }
  } else {
    float* P = (float*)smem;  // [128][68]
#pragma unroll
    for (int mi = 0; mi < 3; mi++) {
      int cob = wm * 48 + mi * 16 + ((lane >> 4) << 2);
      if (cob < 68) {
        f32x4 bia = *(const f32x4*)(L.bias + cob);
#pragma unroll
        for (int ni = 0; ni < 4; ni++) {
          int n = wn * 64 + ni * 16 + (lane & 15);
          f32x4 v = acc[mi][ni];
#pragma unroll
          for (int j = 0; j < 4; j++) v[j] += bia[j];
          *(f32x4*)(P + n * 68 + cob) = v;
        }
      }
    }
    __syncthreads();
    int n = tid >> 1, g2 = tid & 1;
    int p = p0 + n;
    if (p < HW) {
      float d[2];
#pragma unroll
      for (int gg = 0; gg < 2; gg++) {
        const float* row = P + n * 68 + (g2 * 2 + gg) * 17;
        float mx = row[0];
#pragma unroll
        for (int k = 1; k < 17; k++) mx = fmaxf(mx, row[k]);
        float sum = 0.f, dot = 0.f;
#pragma unroll
        for (int k = 0; k < 17; k++) {
          float e = __expf(row[k] - mx);
          sum += e;
          dot += (float)k * e;
        }
        d[gg] = dot / sum;
      }
      *(float2*)(A.out + RO + ((size_t)b * 8400 + L.pos_off + p) * 4 + g2 * 2) = make_float2(d[0], d[1]);
    }
  }
}

// ---------------- host ----------------
extern "C" void kernel_launch(void* const* d_in, const int* in_sizes, int n_in,
                              void* d_out, int out_size, void* d_ws, size_t ws_size,
                              hipStream_t stream) {
  static const int Cs[3] = {768, 384, 192};
  static const int HWs[3] = {400, 1600, 6400};
  static const int Ws[3] = {20, 40, 80};
  static const int POs[3] = {0, 400, 2000};
  static const long TOFF[3] = {0, 4915200, 14745600};
  static const long WTOFF[3] = {0, 663552, 995328};
  static const long GOFF[3] = {0, 9437184, 11796480};
  static const int NT[3] = {4, 13, 50};
  static const int MB[3] = {12, 6, 3};

  char* wsb = (char*)d_ws;
  u16* zp = (u16*)wsb;
  float* avg = (float*)(wsb + 256);
  float* gc = avg + 3 * BSZ * 768;
  float* gr = gc + 3 * BSZ * 768;
  u16* tcT = (u16*)(gr + 3 * BSZ * 768);
  u16* trT = tcT + 34406400;
  u16* wTc = trT + 34406400;
  u16* wTr = wTc + 1161216;
  u16* featT = wTr + 1161216;
  u16* gwc = featT + 34406400;
  u16* gwr = gwc + 12386304;

  hipMemsetAsync(zp, 0, 256, stream);
  hipMemsetAsync(avg, 0, 3 * BSZ * 768 * sizeof(float), stream);
  hipMemsetAsync(wTc, 0, 2 * 1161216ull * 2, stream);

  for (int l = 0; l < 3; l++) {
    const float* pcw = (const float*)d_in[l * 13 + 9];
    const float* prw = (const float*)d_in[l * 13 + 11];
    hipLaunchKernelGGL(k_wprep, dim3(80 * Cs[l] / 256), dim3(256), 0, stream, pcw, wTc + WTOFF[l], Cs[l]);
    hipLaunchKernelGGL(k_wprep, dim3(68 * Cs[l] / 256), dim3(256), 0, stream, prw, wTr + WTOFF[l], Cs[l]);
  }

  {
    PFArgs PF;
    for (int l = 0; l < 3; l++) {
      PF.feat[l] = (const float*)d_in[l * 13 + 0];
      PF.fT[l] = featT + TOFF[l];
    }
    PF.avg = avg;
    int ps1 = BSZ * 7, ps2 = ps1 + BSZ * 25, ptot = ps2 + BSZ * 100;
    hipLaunchKernelGGL(k_prepF2, dim3(ptot), dim3(256), 0, stream, PF, ps1, ps2);
  }

  {
    GArgs GA;
    for (int l = 0; l < 3; l++) {
      const float* const* p = (const float* const*)(d_in + l * 13);
      GA.cfw[l] = p[1]; GA.cfb[l] = p[2];
      GA.rfw[l] = p[3]; GA.rfb[l] = p[4];
    }
    GA.avg = avg; GA.gc = gc; GA.gr = gr;
    int s1 = BSZ * 768, s2 = s1 + BSZ * 384, tot = s2 + BSZ * 192;
    hipLaunchKernelGGL(k_gate, dim3(tot), dim3(256), 0, stream, GA, s1, s2);
  }

  {
    GWArgs GW;
    for (int l = 0; l < 3; l++) {
      const float* const* p = (const float* const*)(d_in + l * 13);
      GW.w0[l] = p[5];
      GW.w1[l] = p[7];
      GW.goff[l] = GOFF[l];
    }
    GW.gc = gc; GW.gr = gr;
    GW.gwc = gwc; GW.gwr = gwr;
    int g1 = BSZ * 288, g2 = g1 + BSZ * 72, gtot = g2 + BSZ * 18;
    hipLaunchKernelGGL(k_wgate, dim3(gtot), dim3(256), 0, stream, GW, g1, g2);
  }

  {
    C1WArgs C1;
    int bstart = 0;
    for (int l = 0; l < 3; l++) {
      const float* const* p = (const float* const*)(d_in + l * 13);
      C1WLvl& L = C1.l[l];
      L.gwc = gwc + GOFF[l];
      L.gwr = gwr + GOFF[l];
      L.b0 = p[6]; L.b1 = p[8];
      L.fT = featT + TOFF[l];
      L.tcT = tcT + TOFF[l];
      L.trT = trT + TOFF[l];
      L.C = Cs[l]; L.HW = HWs[l]; L.ntiles = NT[l]; L.mblks = MB[l];
      L.bstart = bstart;
      L.cnt = BSZ * NT[l] * MB[l];
      bstart += L.cnt;
    }
    hipLaunchKernelGGL(k_conv1p, dim3(bstart), dim3(256), 0, stream, C1);
  }

  {
    C3MArgs C3;
    int bs3 = 0;
    for (int l = 0; l < 3; l++) {
      const float* const* p = (const float* const*)(d_in + l * 13);
      C3Lvl Lc, Lr;
      Lc.inT = tcT + TOFF[l]; Lc.wT = wTc + WTOFF[l]; Lc.bias = p[10];
      Lr.inT = trT + TOFF[l]; Lr.wT = wTr + WTOFF[l]; Lr.bias = p[12];
      Lc.C = Lr.C = Cs[l]; Lc.W = Lr.W = Ws[l]; Lc.H = Lr.H = Ws[l]; Lc.HW = Lr.HW = HWs[l];
      Lc.ntiles = Lr.ntiles = NT[l];
      Lc.bstart = Lr.bstart = bs3;
      Lc.pos_off = Lr.pos_off = POs[l];
      C3.lc[l] = Lc; C3.lr[l] = Lr;
      bs3 += BSZ * NT[l];
    }
    C3.zp = zp; C3.out = (float*)d_out;
    C3.half = bs3;
    hipLaunchKernelGGL(k_conv3m, dim3(2 * bs3), dim3(256), 0, stream, C3);
  }

  hipLaunchKernelGGL(k_anchor, dim3(33), dim3(256), 0, stream, (float*)d_out);
}

// Round 15
// 446.816 us; speedup vs baseline: 1.1983x; 1.1983x over previous
//
#include <hip/hip_runtime.h>
#include <hip/hip_bf16.h>

typedef __attribute__((ext_vector_type(8))) short bf16x8;
typedef __attribute__((ext_vector_type(4))) float f32x4;
typedef __attribute__((ext_vector_type(4))) unsigned short u16x4;
typedef unsigned short u16;
typedef unsigned int u32;

#define BSZ 16
#define RO 10752000
#define AO 11289600
#define SO 11306400

__device__ __forceinline__ float sigm(float x) { return 1.f / (1.f + __expf(-x)); }

__device__ __forceinline__ u16 f2bf(float f) {
  u32 u = __float_as_uint(f);
  u = u + 0x7FFF + ((u >> 16) & 1);
  return (u16)(u >> 16);
}
__device__ __forceinline__ float bf2f(u16 v) { return __uint_as_float(((u32)v) << 16); }

__device__ __forceinline__ void gll16(const void* g, void* l) {
  __builtin_amdgcn_global_load_lds((const __attribute__((address_space(1))) void*)g,
                                   (__attribute__((address_space(3))) void*)l, 16, 0, 0);
}

// bijective XCD-chunked swizzle (m204) — cost-uniform segments only
__device__ __forceinline__ int xswz(int bid, int n) {
  int q = n >> 3, r = n & 7;
  int x = bid & 7, i = bid >> 3;
  return (x < r ? x * (q + 1) : r * (q + 1) + (x - r) * q) + i;
}

// ---------------- anchors ----------------
__global__ __launch_bounds__(256) void k_anchor(float* out) {
  int g = blockIdx.x * 256 + threadIdx.x;
  if (g >= 8400) return;
  int l = g < 400 ? 0 : (g < 2000 ? 1 : 2);
  int off = l == 0 ? 0 : (l == 1 ? 400 : 2000);
  int w = 20 << l;
  float s = (float)(32 >> l);
  int p = g - off;
  int x = p % w, y = p / w;
  out[AO + 2 * g] = x + 0.5f;
  out[AO + 2 * g + 1] = y + 0.5f;
  out[SO + g] = s;
}

// ---------------- featT prep + fused avg partial sums ----------------
struct PFArgs { const float* feat[3]; u16* fT[3]; float* avg; };

__global__ __launch_bounds__(256) void k_prepF2(PFArgs A, int s1, int s2) {
  __shared__ float buf[32][65];
  int bid = blockIdx.x;
  int l = bid >= s2 ? 2 : (bid >= s1 ? 1 : 0);
  int loc = bid - (l == 2 ? s2 : (l == 1 ? s1 : 0));
  int C = 768 >> l, HW = 400 << (2 * l);
  int PT = (HW + 63) / 64;
  int pt = loc % PT, b = loc / PT;
  int p0 = pt * 64;
  int tid = threadIdx.x;
  int cc = tid >> 6, pp = tid & 63;
  int pload = p0 + pp;
  bool lok = pload < HW;
  int plc = lok ? pload : 0;
  int pw = tid >> 2, cg = (tid & 3) * 8;
  bool wok = p0 + pw < HW;
  int rch = tid >> 3, rgp = tid & 7;
  const float* src = A.feat[l] + (size_t)b * C * HW;
  u16* dst = A.fT[l] + (size_t)b * HW * C;
  float* avgb = A.avg + (l * BSZ + b) * 768;
  for (int c0 = 0; c0 < C; c0 += 32) {
#pragma unroll
    for (int j = 0; j < 8; j++) {
      int c = c0 + cc * 8 + j;
      float v = src[(size_t)c * HW + plc];
      buf[cc * 8 + j][pp] = lok ? v : 0.f;
    }
    __syncthreads();
    if (wok) {
      bf16x8 h;
#pragma unroll
      for (int j = 0; j < 8; j++) h[j] = (short)f2bf(buf[cg + j][pw]);
      *(bf16x8*)(dst + (size_t)(p0 + pw) * C + c0 + cg) = h;
    }
    {
      float v = 0.f;
#pragma unroll
      for (int k = 0; k < 8; k++) v += buf[rch][rgp * 8 + k];
      v += __shfl_xor(v, 1);
      v += __shfl_xor(v, 2);
      v += __shfl_xor(v, 4);
      if (rgp == 0) atomicAdd(avgb + c0 + rch, v);
    }
    __syncthreads();
  }
}

// ---------------- gates (avg holds raw sums; fold 1/HW here) ----------------
struct GArgs {
  const float *cfw[3], *cfb[3], *rfw[3], *rfb[3];
  float *avg, *gc, *gr;
};

__global__ __launch_bounds__(256) void k_gate(GArgs A, int s1, int s2) {
  int bid = blockIdx.x;
  int l = bid >= s2 ? 2 : (bid >= s1 ? 1 : 0);
  int loc = bid - (l == 2 ? s2 : (l == 1 ? s1 : 0));
  int C = 768 >> l, HW = 400 << (2 * l);
  float inv = 1.f / (float)HW;
  int co = loc % C, b = loc / C;
  const float* av = A.avg + (l * BSZ + b) * 768;
  float sc = 0.f, sr = 0.f;
  for (int ci = threadIdx.x; ci < C; ci += 256) {
    float v = av[ci];
    sc += A.cfw[l][(size_t)co * C + ci] * v;
    sr += A.rfw[l][(size_t)co * C + ci] * v;
  }
  __shared__ float rc[256], rr[256];
  rc[threadIdx.x] = sc; rr[threadIdx.x] = sr;
  __syncthreads();
  for (int o = 128; o > 0; o >>= 1) {
    if (threadIdx.x < o) { rc[threadIdx.x] += rc[threadIdx.x + o]; rr[threadIdx.x] += rr[threadIdx.x + o]; }
    __syncthreads();
  }
  if (threadIdx.x == 0) {
    A.gc[(l * BSZ + b) * 768 + co] = sigm(rc[0] * inv + A.cfb[l][co]);
    A.gr[(l * BSZ + b) * 768 + co] = sigm(rr[0] * inv + A.rfb[l][co]);
  }
}

// ---------------- gated-weight prep ----------------
struct GWArgs {
  const float *w0[3], *w1[3];
  const float *gc, *gr;
  u16 *gwc, *gwr;
  long goff[3];
};

__global__ __launch_bounds__(256) void k_wgate(GWArgs A, int s1, int s2) {
  int bid = blockIdx.x;
  int l = bid >= s2 ? 2 : (bid >= s1 ? 1 : 0);
  int loc = bid - (l == 2 ? s2 : (l == 1 ? s1 : 0));
  int C = 768 >> l;
  int per_b = (C * C) >> 11;
  int tile = loc % per_b, b = loc / per_b;
  int idx = (tile << 11) + threadIdx.x * 8;
  int co = idx / C, ci = idx - co * C;
  const float* g0 = A.gc + (l * BSZ + b) * 768 + ci;
  const float* g1 = A.gr + (l * BSZ + b) * 768 + ci;
  const float* w0 = A.w0[l] + idx;
  const float* w1 = A.w1[l] + idx;
  f32x4 wa0 = *(const f32x4*)(w0), wb0 = *(const f32x4*)(w0 + 4);
  f32x4 wa1 = *(const f32x4*)(w1), wb1 = *(const f32x4*)(w1 + 4);
  f32x4 ga = *(const f32x4*)(g0), gb = *(const f32x4*)(g0 + 4);
  f32x4 ra = *(const f32x4*)(g1), rb = *(const f32x4*)(g1 + 4);
  bf16x8 h0, h1;
#pragma unroll
  for (int j = 0; j < 4; j++) {
    h0[j] = (short)f2bf(wa0[j] * ga[j]);
    h0[j + 4] = (short)f2bf(wb0[j] * gb[j]);
    h1[j] = (short)f2bf(wa1[j] * ra[j]);
    h1[j + 4] = (short)f2bf(wb1[j] * rb[j]);
  }
  size_t o = A.goff[l] + (size_t)b * C * C + idx;
  *(bf16x8*)(A.gwc + o) = h0;
  *(bf16x8*)(A.gwr + o) = h1;
}

// ---------------- conv3 weight prep: MFMA-fragment-packed layout ----------------
// wf[t][chunk][mt][ks][lane][8]: lane=(co&15)|((koff>>3)<<4), elem=koff&7
__global__ __launch_bounds__(256) void k_wprep(const float* w, u16* dst, int C, int CO) {
  int id = blockIdx.x * 256 + threadIdx.x;
  if (id >= CO * C) return;
  int co = id / C, ci = id - co * C;
  int nch = C >> 6;
  int chunk = ci >> 6;
  int k64 = ci & 63;
  int ks = k64 >> 5, koff = k64 & 31;
  int lane = (co & 15) | ((koff >> 3) << 4);
  int elem = koff & 7;
  int mt = co >> 4;
  const float* s = w + (size_t)id * 9;
#pragma unroll
  for (int t = 0; t < 9; t++) {
    size_t off = (((((size_t)t * nch + chunk) * 6 + mt) * 2 + ks) * 64 + lane) * 8 + elem;
    dst[off] = f2bf(s[t]);
  }
}

// ---------------- conv1p: dual-branch 1x1 GEMM, counted vmcnt + per-level XCD swizzle ----------------
struct C1WLvl {
  const u16 *gwc, *gwr;
  const float *b0, *b1;
  const u16* fT;
  u16 *tcT, *trT;
  int C, HW, ntiles, mblks, bstart, cnt;
};
struct C1WArgs { C1WLvl l[3]; };

__global__ __launch_bounds__(256) void k_conv1p(C1WArgs A) {
  __shared__ char smem[65536];
  int bid = blockIdx.x;
  int li = (bid >= A.l[2].bstart) ? 2 : (bid >= A.l[1].bstart ? 1 : 0);
  const C1WLvl& L = A.l[li];
  int loc = xswz(bid - L.bstart, L.cnt);
  int mb = loc % L.mblks;
  int t2 = loc / L.mblks;
  int nt = t2 % L.ntiles;
  int b = t2 / L.ntiles;
  const int C = L.C, HW = L.HW;
  int p0 = nt * 128, co0 = mb * 64;
  int tid = threadIdx.x, lane = tid & 63, w = tid >> 6;
  int wm = w >> 1, wn = w & 1;
  const u16* fTb = L.fT + (size_t)b * HW * C;
  const u16* gw0 = L.gwc + (size_t)b * C * C;
  const u16* gw1 = L.gwr + (size_t)b * C * C;
  int sl8 = lane & 7;

  const u16* bsrc[4];
#pragma unroll
  for (int i = 0; i < 4; i++) {
    int r = w * 32 + i * 8 + (lane >> 3);
    int p = p0 + r;
    if (p >= HW) p = HW - 1;
    bsrc[i] = fTb + (size_t)p * C + ((sl8 ^ (r & 7)) << 3);
  }
  const u16 *a0src[2], *a1src[2];
#pragma unroll
  for (int i = 0; i < 2; i++) {
    int r = w * 16 + i * 8 + (lane >> 3);
    a0src[i] = gw0 + (size_t)(co0 + r) * C + ((sl8 ^ (r & 7)) << 3);
    a1src[i] = gw1 + (size_t)(co0 + r) * C + ((sl8 ^ (r & 7)) << 3);
  }
  int aoff[2][2], boff[2][4];
#pragma unroll
  for (int ks = 0; ks < 2; ks++) {
    int sl = ks * 4 + (lane >> 4);
#pragma unroll
    for (int mi = 0; mi < 2; mi++) {
      int ar = wm * 32 + mi * 16 + (lane & 15);
      aoff[ks][mi] = ar * 128 + ((sl ^ (ar & 7)) << 4);
    }
#pragma unroll
    for (int ni = 0; ni < 4; ni++) {
      int br = wn * 64 + ni * 16 + (lane & 15);
      boff[ks][ni] = br * 128 + ((sl ^ (br & 7)) << 4);
    }
  }

  f32x4 acc0[2][4], acc1[2][4];
#pragma unroll
  for (int mi = 0; mi < 2; mi++)
#pragma unroll
    for (int ni = 0; ni < 4; ni++) { acc0[mi][ni] = (f32x4){0.f,0.f,0.f,0.f}; acc1[mi][ni] = (f32x4){0.f,0.f,0.f,0.f}; }

  const int nchunk = C >> 6;
  {
    char* buf = smem;
#pragma unroll
    for (int i = 0; i < 4; i++) gll16(bsrc[i], buf + 16384 + (w * 32 + i * 8) * 128);
#pragma unroll
    for (int i = 0; i < 2; i++) {
      gll16(a0src[i], buf + (w * 16 + i * 8) * 128);
      gll16(a1src[i], buf + 8192 + (w * 16 + i * 8) * 128);
    }
  }

  int cur = 0;
  for (int c = 0; c < nchunk; c++) {
    if (c + 1 < nchunk) {
      int cb = (c + 1) << 6;
      char* buf = smem + ((cur ^ 1) << 15);
#pragma unroll
      for (int i = 0; i < 4; i++) gll16(bsrc[i] + cb, buf + 16384 + (w * 32 + i * 8) * 128);
#pragma unroll
      for (int i = 0; i < 2; i++) {
        gll16(a0src[i] + cb, buf + (w * 16 + i * 8) * 128);
        gll16(a1src[i] + cb, buf + 8192 + (w * 16 + i * 8) * 128);
      }
      asm volatile("s_waitcnt vmcnt(8)" ::: "memory");
    } else {
      asm volatile("s_waitcnt vmcnt(0)" ::: "memory");
    }
    __builtin_amdgcn_sched_barrier(0);
    __builtin_amdgcn_s_barrier();
    __builtin_amdgcn_sched_barrier(0);

    char* B0 = smem + (cur << 15);
#pragma unroll
    for (int ks = 0; ks < 2; ks++) {
      bf16x8 a0[2], a1[2], bf[4];
#pragma unroll
      for (int mi = 0; mi < 2; mi++) {
        a0[mi] = *(const bf16x8*)(B0 + aoff[ks][mi]);
        a1[mi] = *(const bf16x8*)(B0 + 8192 + aoff[ks][mi]);
      }
#pragma unroll
      for (int ni = 0; ni < 4; ni++) bf[ni] = *(const bf16x8*)(B0 + 16384 + boff[ks][ni]);
#pragma unroll
      for (int mi = 0; mi < 2; mi++)
#pragma unroll
        for (int ni = 0; ni < 4; ni++) {
          acc0[mi][ni] = __builtin_amdgcn_mfma_f32_16x16x32_bf16(a0[mi], bf[ni], acc0[mi][ni], 0, 0, 0);
          acc1[mi][ni] = __builtin_amdgcn_mfma_f32_16x16x32_bf16(a1[mi], bf[ni], acc1[mi][ni], 0, 0, 0);
        }
    }
    __builtin_amdgcn_sched_barrier(0);
    __builtin_amdgcn_s_barrier();
    __builtin_amdgcn_sched_barrier(0);
    cur ^= 1;
  }

#pragma unroll
  for (int mi = 0; mi < 2; mi++) {
    int cob = co0 + wm * 32 + mi * 16 + ((lane >> 4) << 2);
    f32x4 bia0 = *(const f32x4*)(L.b0 + cob);
    f32x4 bia1 = *(const f32x4*)(L.b1 + cob);
#pragma unroll
    for (int ni = 0; ni < 4; ni++) {
      int p = p0 + wn * 64 + ni * 16 + (lane & 15);
      if (p >= HW) continue;
      u16x4 res = *(const u16x4*)(fTb + (size_t)p * C + cob);
      u16x4 o0, o1;
#pragma unroll
      for (int j = 0; j < 4; j++) {
        float x0 = acc0[mi][ni][j] + bia0[j];
        o0[j] = f2bf(x0 * sigm(x0) + bf2f(res[j]));
        float x1 = acc1[mi][ni][j] + bia1[j];
        o1[j] = f2bf(x1 * sigm(x1));
      }
      size_t off = ((size_t)b * HW + p) * C + cob;
      *(u16x4*)(L.tcT + off) = o0;
      *(u16x4*)(L.trT + off) = o1;
    }
  }
}

// ---------------- conv3m: A from fragment-packed global (coalesced, L2-hot), B-only LDS dbuf ----------------
struct C3Lvl {
  const u16* inT;
  const u16* wT;     // fragment-packed
  const float* bias;
  int C, W, H, HW, ntiles, bstart, pos_off;
};
struct C3MArgs { C3Lvl lc[3]; C3Lvl lr[3]; const u16* zp; float* out; int half; };

__global__ __launch_bounds__(256) void k_conv3m(C3MArgs A) {
  __shared__ char smem[34816];  // 2 x B 16K; reg epilogue P[128][68] f32 = 34816
  int rb = blockIdx.x;
  bool isReg = rb >= A.half;
  int bid = isReg ? rb - A.half : rb;
  const C3Lvl* lv = isReg ? A.lr : A.lc;
  int li = (bid >= lv[2].bstart) ? 2 : (bid >= lv[1].bstart ? 1 : 0);
  const C3Lvl& L = lv[li];
  int loc = bid - L.bstart;
  int nt = loc % L.ntiles;
  int b = loc / L.ntiles;
  const int C = L.C, W = L.W, H = L.H, HW = L.HW;
  int p0 = nt * 128;
  int tid = threadIdx.x, lane = tid & 63, w = tid >> 6;
  int wm = w >> 1, wn = w & 1;
  int sl8 = lane & 7;
  const u16* inb = L.inT + (size_t)b * HW * C;
  const int nchunk = C >> 6;

  int px[4], py[4];
  bool pv[4];
  const u16* bbase[4];
#pragma unroll
  for (int i = 0; i < 4; i++) {
    int r = w * 32 + i * 8 + (lane >> 3);
    int p = p0 + r;
    pv[i] = p < HW;
    int pp = pv[i] ? p : 0;
    px[i] = pp % W;
    py[i] = pp / W;
    bbase[i] = inb + (size_t)pp * C + ((sl8 ^ (r & 7)) << 3);
  }
  // fragment-packed A base: per-lane offset is lane*8 (coalesced)
  const u16* wfl = L.wT + (size_t)lane * 8;

  int boff[2][4];
#pragma unroll
  for (int ks = 0; ks < 2; ks++) {
    int sl = ks * 4 + (lane >> 4);
#pragma unroll
    for (int ni = 0; ni < 4; ni++) {
      int br = wn * 64 + ni * 16 + (lane & 15);
      boff[ks][ni] = br * 128 + ((sl ^ (br & 7)) << 4);
    }
  }

  f32x4 acc[3][4];
#pragma unroll
  for (int mi = 0; mi < 3; mi++)
#pragma unroll
    for (int ni = 0; ni < 4; ni++) acc[mi][ni] = (f32x4){0.f,0.f,0.f,0.f};

  const int total = 9 * nchunk;

  auto STAGEB = [&](int t, int cb, char* buf) {
    int dy = t / 3 - 1, dx = t - (t / 3) * 3 - 1;
    long shift = (long)(dy * W + dx) * C;
#pragma unroll
    for (int i = 0; i < 4; i++) {
      int xx = px[i] + dx, yy = py[i] + dy;
      bool ok = pv[i] && ((unsigned)xx < (unsigned)W) && ((unsigned)yy < (unsigned)H);
      const void* src = ok ? (const void*)(bbase[i] + shift + cb) : (const void*)A.zp;
      gll16(src, buf + (w * 32 + i * 8) * 128);
    }
  };
  // fragment index: (((t*nch + c)*6 + mt)*2 + ks)*512 elems from level base
  auto LOADA = [&](bf16x8 (&dst)[6], int tt, int cc) {
    size_t base = ((size_t)tt * nchunk + cc) * 6;
#pragma unroll
    for (int ks = 0; ks < 2; ks++)
#pragma unroll
      for (int mi = 0; mi < 3; mi++)
        dst[ks * 3 + mi] = *(const bf16x8*)(wfl + ((base + wm * 3 + mi) * 2 + ks) * 512);
  };

  bf16x8 aA[6], aB[6];
  STAGEB(0, 0, smem);
  LOADA(aA, 0, 0);

  int cur = 0, t = 0, c = 0;
  auto STEP = [&](bf16x8 (&use)[6], bf16x8 (&pre)[6], int s) {
    int tn = t + 1, cn = c;
    if (tn == 9) { tn = 0; cn = c + 1; }
    if (s + 1 < total) {
      STAGEB(tn, cn << 6, smem + ((cur ^ 1) << 14));
      LOADA(pre, tn, cn);
      __builtin_amdgcn_sched_barrier(0);
      asm volatile("s_waitcnt vmcnt(10)" ::: "memory");
    } else {
      asm volatile("s_waitcnt vmcnt(0)" ::: "memory");
    }
    __builtin_amdgcn_sched_barrier(0);
    __builtin_amdgcn_s_barrier();
    __builtin_amdgcn_sched_barrier(0);
    char* B0 = smem + (cur << 14);
#pragma unroll
    for (int ks = 0; ks < 2; ks++) {
      bf16x8 bf[4];
#pragma unroll
      for (int ni = 0; ni < 4; ni++) bf[ni] = *(const bf16x8*)(B0 + boff[ks][ni]);
#pragma unroll
      for (int mi = 0; mi < 3; mi++)
#pragma unroll
        for (int ni = 0; ni < 4; ni++)
          acc[mi][ni] = __builtin_amdgcn_mfma_f32_16x16x32_bf16(use[ks * 3 + mi], bf[ni], acc[mi][ni], 0, 0, 0);
    }
    __builtin_amdgcn_sched_barrier(0);
    __builtin_amdgcn_s_barrier();
    __builtin_amdgcn_sched_barrier(0);
    cur ^= 1; t = tn; c = cn;
  };

  int s = 0;
  while (true) {
    STEP(aA, aB, s); if (++s == total) break;
    STEP(aB, aA, s); if (++s == total) break;
  }

  if (!isReg) {
#pragma unroll
    for (int mi = 0; mi < 3; mi++) {
      int cob = wm * 48 + mi * 16 + ((lane >> 4) << 2);
      if (cob >= 80) continue;
      f32x4 bia = *(const f32x4*)(L.bias + cob);
#pragma unroll
      for (int ni = 0; ni < 4; ni++) {
        int p = p0 + wn * 64 + ni * 16 + (lane & 15);
        if (p >= HW) continue;
#pragma unroll
        for (int j = 0; j < 4; j++)
          A.out[(size_t)(b * 80 + cob + j) * 8400 + L.pos_off + p] = sigm(acc[mi][ni][j] + bia[j]);
      }
    }
  } else {
    float* P = (float*)smem;  // [128][68]
#pragma unroll
    for (int mi = 0; mi < 3; mi++) {
      int cob = wm * 48 + mi * 16 + ((lane >> 4) << 2);
      if (cob < 68) {
        f32x4 bia = *(const f32x4*)(L.bias + cob);
#pragma unroll
        for (int ni = 0; ni < 4; ni++) {
          int n = wn * 64 + ni * 16 + (lane & 15);
          f32x4 v = acc[mi][ni];
#pragma unroll
          for (int j = 0; j < 4; j++) v[j] += bia[j];
          *(f32x4*)(P + n * 68 + cob) = v;
        }
      }
    }
    __syncthreads();
    int n = tid >> 1, g2 = tid & 1;
    int p = p0 + n;
    if (p < HW) {
      float d[2];
#pragma unroll
      for (int gg = 0; gg < 2; gg++) {
        const float* row = P + n * 68 + (g2 * 2 + gg) * 17;
        float mx = row[0];
#pragma unroll
        for (int k = 1; k < 17; k++) mx = fmaxf(mx, row[k]);
        float sum = 0.f, dot = 0.f;
#pragma unroll
        for (int k = 0; k < 17; k++) {
          float e = __expf(row[k] - mx);
          sum += e;
          dot += (float)k * e;
        }
        d[gg] = dot / sum;
      }
      *(float2*)(A.out + RO + ((size_t)b * 8400 + L.pos_off + p) * 4 + g2 * 2) = make_float2(d[0], d[1]);
    }
  }
}

// ---------------- host ----------------
extern "C" void kernel_launch(void* const* d_in, const int* in_sizes, int n_in,
                              void* d_out, int out_size, void* d_ws, size_t ws_size,
                              hipStream_t stream) {
  static const int Cs[3] = {768, 384, 192};
  static const int HWs[3] = {400, 1600, 6400};
  static const int Ws[3] = {20, 40, 80};
  static const int POs[3] = {0, 400, 2000};
  static const long TOFF[3] = {0, 4915200, 14745600};
  static const long WTOFF[3] = {0, 663552, 995328};
  static const long GOFF[3] = {0, 9437184, 11796480};
  static const int NT[3] = {4, 13, 50};
  static const int MB[3] = {12, 6, 3};

  char* wsb = (char*)d_ws;
  u16* zp = (u16*)wsb;
  float* avg = (float*)(wsb + 256);
  float* gc = avg + 3 * BSZ * 768;
  float* gr = gc + 3 * BSZ * 768;
  u16* tcT = (u16*)(gr + 3 * BSZ * 768);
  u16* trT = tcT + 34406400;
  u16* wTc = trT + 34406400;
  u16* wTr = wTc + 1161216;
  u16* featT = wTr + 1161216;
  u16* gwc = featT + 34406400;
  u16* gwr = gwc + 12386304;

  hipMemsetAsync(zp, 0, 256, stream);
  hipMemsetAsync(avg, 0, 3 * BSZ * 768 * sizeof(float), stream);
  hipMemsetAsync(wTc, 0, 2 * 1161216ull * 2, stream);

  for (int l = 0; l < 3; l++) {
    const float* pcw = (const float*)d_in[l * 13 + 9];
    const float* prw = (const float*)d_in[l * 13 + 11];
    hipLaunchKernelGGL(k_wprep, dim3((80 * Cs[l] + 255) / 256), dim3(256), 0, stream, pcw, wTc + WTOFF[l], Cs[l], 80);
    hipLaunchKernelGGL(k_wprep, dim3((68 * Cs[l] + 255) / 256), dim3(256), 0, stream, prw, wTr + WTOFF[l], Cs[l], 68);
  }

  {
    PFArgs PF;
    for (int l = 0; l < 3; l++) {
      PF.feat[l] = (const float*)d_in[l * 13 + 0];
      PF.fT[l] = featT + TOFF[l];
    }
    PF.avg = avg;
    int ps1 = BSZ * 7, ps2 = ps1 + BSZ * 25, ptot = ps2 + BSZ * 100;
    hipLaunchKernelGGL(k_prepF2, dim3(ptot), dim3(256), 0, stream, PF, ps1, ps2);
  }

  {
    GArgs GA;
    for (int l = 0; l < 3; l++) {
      const float* const* p = (const float* const*)(d_in + l * 13);
      GA.cfw[l] = p[1]; GA.cfb[l] = p[2];
      GA.rfw[l] = p[3]; GA.rfb[l] = p[4];
    }
    GA.avg = avg; GA.gc = gc; GA.gr = gr;
    int s1 = BSZ * 768, s2 = s1 + BSZ * 384, tot = s2 + BSZ * 192;
    hipLaunchKernelGGL(k_gate, dim3(tot), dim3(256), 0, stream, GA, s1, s2);
  }

  {
    GWArgs GW;
    for (int l = 0; l < 3; l++) {
      const float* const* p = (const float* const*)(d_in + l * 13);
      GW.w0[l] = p[5];
      GW.w1[l] = p[7];
      GW.goff[l] = GOFF[l];
    }
    GW.gc = gc; GW.gr = gr;
    GW.gwc = gwc; GW.gwr = gwr;
    int g1 = BSZ * 288, g2 = g1 + BSZ * 72, gtot = g2 + BSZ * 18;
    hipLaunchKernelGGL(k_wgate, dim3(gtot), dim3(256), 0, stream, GW, g1, g2);
  }

  {
    C1WArgs C1;
    int bstart = 0;
    for (int l = 0; l < 3; l++) {
      const float* const* p = (const float* const*)(d_in + l * 13);
      C1WLvl& L = C1.l[l];
      L.gwc = gwc + GOFF[l];
      L.gwr = gwr + GOFF[l];
      L.b0 = p[6]; L.b1 = p[8];
      L.fT = featT + TOFF[l];
      L.tcT = tcT + TOFF[l];
      L.trT = trT + TOFF[l];
      L.C = Cs[l]; L.HW = HWs[l]; L.ntiles = NT[l]; L.mblks = MB[l];
      L.bstart = bstart;
      L.cnt = BSZ * NT[l] * MB[l];
      bstart += L.cnt;
    }
    hipLaunchKernelGGL(k_conv1p, dim3(bstart), dim3(256), 0, stream, C1);
  }

  {
    C3MArgs C3;
    int bs3 = 0;
    for (int l = 0; l < 3; l++) {
      const float* const* p = (const float* const*)(d_in + l * 13);
      C3Lvl Lc, Lr;
      Lc.inT = tcT + TOFF[l]; Lc.wT = wTc + WTOFF[l]; Lc.bias = p[10];
      Lr.inT = trT + TOFF[l]; Lr.wT = wTr + WTOFF[l]; Lr.bias = p[12];
      Lc.C = Lr.C = Cs[l]; Lc.W = Lr.W = Ws[l]; Lc.H = Lr.H = Ws[l]; Lc.HW = Lr.HW = HWs[l];
      Lc.ntiles = Lr.ntiles = NT[l];
      Lc.bstart = Lr.bstart = bs3;
      Lc.pos_off = Lr.pos_off = POs[l];
      C3.lc[l] = Lc; C3.lr[l] = Lr;
      bs3 += BSZ * NT[l];
    }
    C3.zp = zp; C3.out = (float*)d_out;
    C3.half = bs3;
    hipLaunchKernelGGL(k_conv3m, dim3(2 * bs3), dim3(256), 0, stream, C3);
  }

  hipLaunchKernelGGL(k_anchor, dim3(33), dim3(256), 0, stream, (float*)d_out);
}

// Round 16
// 395.059 us; speedup vs baseline: 1.3553x; 1.1310x over previous
//
#include <hip/hip_runtime.h>
#include <hip/hip_bf16.h>

typedef __attribute__((ext_vector_type(8))) short bf16x8;
typedef __attribute__((ext_vector_type(4))) float f32x4;
typedef __attribute__((ext_vector_type(4))) unsigned short u16x4;
typedef unsigned short u16;
typedef unsigned int u32;

#define BSZ 16
#define RO 10752000
#define AO 11289600
#define SO 11306400

__device__ __forceinline__ float sigm(float x) { return 1.f / (1.f + __expf(-x)); }

__device__ __forceinline__ u16 f2bf(float f) {
  u32 u = __float_as_uint(f);
  u = u + 0x7FFF + ((u >> 16) & 1);
  return (u16)(u >> 16);
}
__device__ __forceinline__ float bf2f(u16 v) { return __uint_as_float(((u32)v) << 16); }

__device__ __forceinline__ void gll16(const void* g, void* l) {
  __builtin_amdgcn_global_load_lds((const __attribute__((address_space(1))) void*)g,
                                   (__attribute__((address_space(3))) void*)l, 16, 0, 0);
}

// bijective XCD-chunked swizzle (m204) — cost-uniform segments only
__device__ __forceinline__ int xswz(int bid, int n) {
  int q = n >> 3, r = n & 7;
  int x = bid & 7, i = bid >> 3;
  return (x < r ? x * (q + 1) : r * (q + 1) + (x - r) * q) + i;
}

// ---------------- anchors ----------------
__global__ __launch_bounds__(256) void k_anchor(float* out) {
  int g = blockIdx.x * 256 + threadIdx.x;
  if (g >= 8400) return;
  int l = g < 400 ? 0 : (g < 2000 ? 1 : 2);
  int off = l == 0 ? 0 : (l == 1 ? 400 : 2000);
  int w = 20 << l;
  float s = (float)(32 >> l);
  int p = g - off;
  int x = p % w, y = p / w;
  out[AO + 2 * g] = x + 0.5f;
  out[AO + 2 * g + 1] = y + 0.5f;
  out[SO + g] = s;
}

// ---------------- featT prep + fused avg partial sums ----------------
struct PFArgs { const float* feat[3]; u16* fT[3]; float* avg; };

__global__ __launch_bounds__(256) void k_prepF2(PFArgs A, int s1, int s2) {
  __shared__ float buf[32][65];
  int bid = blockIdx.x;
  int l = bid >= s2 ? 2 : (bid >= s1 ? 1 : 0);
  int loc = bid - (l == 2 ? s2 : (l == 1 ? s1 : 0));
  int C = 768 >> l, HW = 400 << (2 * l);
  int PT = (HW + 63) / 64;
  int pt = loc % PT, b = loc / PT;
  int p0 = pt * 64;
  int tid = threadIdx.x;
  int cc = tid >> 6, pp = tid & 63;
  int pload = p0 + pp;
  bool lok = pload < HW;
  int plc = lok ? pload : 0;
  int pw = tid >> 2, cg = (tid & 3) * 8;
  bool wok = p0 + pw < HW;
  int rch = tid >> 3, rgp = tid & 7;
  const float* src = A.feat[l] + (size_t)b * C * HW;
  u16* dst = A.fT[l] + (size_t)b * HW * C;
  float* avgb = A.avg + (l * BSZ + b) * 768;
  for (int c0 = 0; c0 < C; c0 += 32) {
#pragma unroll
    for (int j = 0; j < 8; j++) {
      int c = c0 + cc * 8 + j;
      float v = src[(size_t)c * HW + plc];
      buf[cc * 8 + j][pp] = lok ? v : 0.f;
    }
    __syncthreads();
    if (wok) {
      bf16x8 h;
#pragma unroll
      for (int j = 0; j < 8; j++) h[j] = (short)f2bf(buf[cg + j][pw]);
      *(bf16x8*)(dst + (size_t)(p0 + pw) * C + c0 + cg) = h;
    }
    {
      float v = 0.f;
#pragma unroll
      for (int k = 0; k < 8; k++) v += buf[rch][rgp * 8 + k];
      v += __shfl_xor(v, 1);
      v += __shfl_xor(v, 2);
      v += __shfl_xor(v, 4);
      if (rgp == 0) atomicAdd(avgb + c0 + rch, v);
    }
    __syncthreads();
  }
}

// ---------------- gates (avg holds raw sums; fold 1/HW here) ----------------
struct GArgs {
  const float *cfw[3], *cfb[3], *rfw[3], *rfb[3];
  float *avg, *gc, *gr;
};

__global__ __launch_bounds__(256) void k_gate(GArgs A, int s1, int s2) {
  int bid = blockIdx.x;
  int l = bid >= s2 ? 2 : (bid >= s1 ? 1 : 0);
  int loc = bid - (l == 2 ? s2 : (l == 1 ? s1 : 0));
  int C = 768 >> l, HW = 400 << (2 * l);
  float inv = 1.f / (float)HW;
  int co = loc % C, b = loc / C;
  const float* av = A.avg + (l * BSZ + b) * 768;
  float sc = 0.f, sr = 0.f;
  for (int ci = threadIdx.x; ci < C; ci += 256) {
    float v = av[ci];
    sc += A.cfw[l][(size_t)co * C + ci] * v;
    sr += A.rfw[l][(size_t)co * C + ci] * v;
  }
  __shared__ float rc[256], rr[256];
  rc[threadIdx.x] = sc; rr[threadIdx.x] = sr;
  __syncthreads();
  for (int o = 128; o > 0; o >>= 1) {
    if (threadIdx.x < o) { rc[threadIdx.x] += rc[threadIdx.x + o]; rr[threadIdx.x] += rr[threadIdx.x + o]; }
    __syncthreads();
  }
  if (threadIdx.x == 0) {
    A.gc[(l * BSZ + b) * 768 + co] = sigm(rc[0] * inv + A.cfb[l][co]);
    A.gr[(l * BSZ + b) * 768 + co] = sigm(rr[0] * inv + A.rfb[l][co]);
  }
}

// ---------------- gated-weight prep ----------------
struct GWArgs {
  const float *w0[3], *w1[3];
  const float *gc, *gr;
  u16 *gwc, *gwr;
  long goff[3];
};

__global__ __launch_bounds__(256) void k_wgate(GWArgs A, int s1, int s2) {
  int bid = blockIdx.x;
  int l = bid >= s2 ? 2 : (bid >= s1 ? 1 : 0);
  int loc = bid - (l == 2 ? s2 : (l == 1 ? s1 : 0));
  int C = 768 >> l;
  int per_b = (C * C) >> 11;
  int tile = loc % per_b, b = loc / per_b;
  int idx = (tile << 11) + threadIdx.x * 8;
  int co = idx / C, ci = idx - co * C;
  const float* g0 = A.gc + (l * BSZ + b) * 768 + ci;
  const float* g1 = A.gr + (l * BSZ + b) * 768 + ci;
  const float* w0 = A.w0[l] + idx;
  const float* w1 = A.w1[l] + idx;
  f32x4 wa0 = *(const f32x4*)(w0), wb0 = *(const f32x4*)(w0 + 4);
  f32x4 wa1 = *(const f32x4*)(w1), wb1 = *(const f32x4*)(w1 + 4);
  f32x4 ga = *(const f32x4*)(g0), gb = *(const f32x4*)(g0 + 4);
  f32x4 ra = *(const f32x4*)(g1), rb = *(const f32x4*)(g1 + 4);
  bf16x8 h0, h1;
#pragma unroll
  for (int j = 0; j < 4; j++) {
    h0[j] = (short)f2bf(wa0[j] * ga[j]);
    h0[j + 4] = (short)f2bf(wb0[j] * gb[j]);
    h1[j] = (short)f2bf(wa1[j] * ra[j]);
    h1[j + 4] = (short)f2bf(wb1[j] * rb[j]);
  }
  size_t o = A.goff[l] + (size_t)b * C * C + idx;
  *(bf16x8*)(A.gwc + o) = h0;
  *(bf16x8*)(A.gwr + o) = h1;
}

// ---------------- weight pre-transpose for conv3 (R12 layout: wT[t][96][C]) ----------------
__global__ __launch_bounds__(256) void k_wprep(const float* w, u16* dst, int C) {
  int id = blockIdx.x * 256 + threadIdx.x;
  int co = id / C, ci = id - co * C;
  const float* s = w + (size_t)id * 9;
#pragma unroll
  for (int t = 0; t < 9; t++) dst[((size_t)(t * 96 + co)) * C + ci] = f2bf(s[t]);
}

// ---------------- conv1p: dual-branch 1x1 GEMM, counted vmcnt + per-level XCD swizzle ----------------
struct C1WLvl {
  const u16 *gwc, *gwr;
  const float *b0, *b1;
  const u16* fT;
  u16 *tcT, *trT;
  int C, HW, ntiles, mblks, bstart, cnt;
};
struct C1WArgs { C1WLvl l[3]; };

__global__ __launch_bounds__(256) void k_conv1p(C1WArgs A) {
  __shared__ char smem[65536];
  int bid = blockIdx.x;
  int li = (bid >= A.l[2].bstart) ? 2 : (bid >= A.l[1].bstart ? 1 : 0);
  const C1WLvl& L = A.l[li];
  int loc = xswz(bid - L.bstart, L.cnt);
  int mb = loc % L.mblks;
  int t2 = loc / L.mblks;
  int nt = t2 % L.ntiles;
  int b = t2 / L.ntiles;
  const int C = L.C, HW = L.HW;
  int p0 = nt * 128, co0 = mb * 64;
  int tid = threadIdx.x, lane = tid & 63, w = tid >> 6;
  int wm = w >> 1, wn = w & 1;
  const u16* fTb = L.fT + (size_t)b * HW * C;
  const u16* gw0 = L.gwc + (size_t)b * C * C;
  const u16* gw1 = L.gwr + (size_t)b * C * C;
  int sl8 = lane & 7;

  const u16* bsrc[4];
#pragma unroll
  for (int i = 0; i < 4; i++) {
    int r = w * 32 + i * 8 + (lane >> 3);
    int p = p0 + r;
    if (p >= HW) p = HW - 1;
    bsrc[i] = fTb + (size_t)p * C + ((sl8 ^ (r & 7)) << 3);
  }
  const u16 *a0src[2], *a1src[2];
#pragma unroll
  for (int i = 0; i < 2; i++) {
    int r = w * 16 + i * 8 + (lane >> 3);
    a0src[i] = gw0 + (size_t)(co0 + r) * C + ((sl8 ^ (r & 7)) << 3);
    a1src[i] = gw1 + (size_t)(co0 + r) * C + ((sl8 ^ (r & 7)) << 3);
  }
  int aoff[2][2], boff[2][4];
#pragma unroll
  for (int ks = 0; ks < 2; ks++) {
    int sl = ks * 4 + (lane >> 4);
#pragma unroll
    for (int mi = 0; mi < 2; mi++) {
      int ar = wm * 32 + mi * 16 + (lane & 15);
      aoff[ks][mi] = ar * 128 + ((sl ^ (ar & 7)) << 4);
    }
#pragma unroll
    for (int ni = 0; ni < 4; ni++) {
      int br = wn * 64 + ni * 16 + (lane & 15);
      boff[ks][ni] = br * 128 + ((sl ^ (br & 7)) << 4);
    }
  }

  f32x4 acc0[2][4], acc1[2][4];
#pragma unroll
  for (int mi = 0; mi < 2; mi++)
#pragma unroll
    for (int ni = 0; ni < 4; ni++) { acc0[mi][ni] = (f32x4){0.f,0.f,0.f,0.f}; acc1[mi][ni] = (f32x4){0.f,0.f,0.f,0.f}; }

  const int nchunk = C >> 6;
  {
    char* buf = smem;
#pragma unroll
    for (int i = 0; i < 4; i++) gll16(bsrc[i], buf + 16384 + (w * 32 + i * 8) * 128);
#pragma unroll
    for (int i = 0; i < 2; i++) {
      gll16(a0src[i], buf + (w * 16 + i * 8) * 128);
      gll16(a1src[i], buf + 8192 + (w * 16 + i * 8) * 128);
    }
  }

  int cur = 0;
  for (int c = 0; c < nchunk; c++) {
    if (c + 1 < nchunk) {
      int cb = (c + 1) << 6;
      char* buf = smem + ((cur ^ 1) << 15);
#pragma unroll
      for (int i = 0; i < 4; i++) gll16(bsrc[i] + cb, buf + 16384 + (w * 32 + i * 8) * 128);
#pragma unroll
      for (int i = 0; i < 2; i++) {
        gll16(a0src[i] + cb, buf + (w * 16 + i * 8) * 128);
        gll16(a1src[i] + cb, buf + 8192 + (w * 16 + i * 8) * 128);
      }
      asm volatile("s_waitcnt vmcnt(8)" ::: "memory");
    } else {
      asm volatile("s_waitcnt vmcnt(0)" ::: "memory");
    }
    __builtin_amdgcn_sched_barrier(0);
    __builtin_amdgcn_s_barrier();
    __builtin_amdgcn_sched_barrier(0);

    char* B0 = smem + (cur << 15);
    __builtin_amdgcn_s_setprio(1);
#pragma unroll
    for (int ks = 0; ks < 2; ks++) {
      bf16x8 a0[2], a1[2], bf[4];
#pragma unroll
      for (int mi = 0; mi < 2; mi++) {
        a0[mi] = *(const bf16x8*)(B0 + aoff[ks][mi]);
        a1[mi] = *(const bf16x8*)(B0 + 8192 + aoff[ks][mi]);
      }
#pragma unroll
      for (int ni = 0; ni < 4; ni++) bf[ni] = *(const bf16x8*)(B0 + 16384 + boff[ks][ni]);
#pragma unroll
      for (int mi = 0; mi < 2; mi++)
#pragma unroll
        for (int ni = 0; ni < 4; ni++) {
          acc0[mi][ni] = __builtin_amdgcn_mfma_f32_16x16x32_bf16(a0[mi], bf[ni], acc0[mi][ni], 0, 0, 0);
          acc1[mi][ni] = __builtin_amdgcn_mfma_f32_16x16x32_bf16(a1[mi], bf[ni], acc1[mi][ni], 0, 0, 0);
        }
    }
    __builtin_amdgcn_s_setprio(0);
    __builtin_amdgcn_sched_barrier(0);
    __builtin_amdgcn_s_barrier();
    __builtin_amdgcn_sched_barrier(0);
    cur ^= 1;
  }

#pragma unroll
  for (int mi = 0; mi < 2; mi++) {
    int cob = co0 + wm * 32 + mi * 16 + ((lane >> 4) << 2);
    f32x4 bia0 = *(const f32x4*)(L.b0 + cob);
    f32x4 bia1 = *(const f32x4*)(L.b1 + cob);
#pragma unroll
    for (int ni = 0; ni < 4; ni++) {
      int p = p0 + wn * 64 + ni * 16 + (lane & 15);
      if (p >= HW) continue;
      u16x4 res = *(const u16x4*)(fTb + (size_t)p * C + cob);
      u16x4 o0, o1;
#pragma unroll
      for (int j = 0; j < 4; j++) {
        float x0 = acc0[mi][ni][j] + bia0[j];
        o0[j] = f2bf(x0 * sigm(x0) + bf2f(res[j]));
        float x1 = acc1[mi][ni][j] + bia1[j];
        o1[j] = f2bf(x1 * sigm(x1));
      }
      size_t off = ((size_t)b * HW + p) * C + cob;
      *(u16x4*)(L.tcT + off) = o0;
      *(u16x4*)(L.trT + off) = o1;
    }
  }
}

// ---------------- conv3m: cls+reg merged, tap-inner, 2-phase dbuf + counted vmcnt (R12) ----------------
struct C3Lvl {
  const u16* inT;
  const u16* wT;
  const float* bias;
  int C, W, H, HW, ntiles, bstart, pos_off;
};
struct C3MArgs { C3Lvl lc[3]; C3Lvl lr[3]; const u16* zp; float* out; int half; };

__global__ __launch_bounds__(256) void k_conv3m(C3MArgs A) {
  __shared__ char smem[57344];
  int rb = blockIdx.x;
  bool isReg = rb >= A.half;
  int bid = isReg ? rb - A.half : rb;
  const C3Lvl* lv = isReg ? A.lr : A.lc;
  int li = (bid >= lv[2].bstart) ? 2 : (bid >= lv[1].bstart ? 1 : 0);
  const C3Lvl& L = lv[li];
  int loc = bid - L.bstart;
  int nt = loc % L.ntiles;
  int b = loc / L.ntiles;
  const int C = L.C, W = L.W, H = L.H, HW = L.HW;
  int p0 = nt * 128;
  int tid = threadIdx.x, lane = tid & 63, w = tid >> 6;
  int wm = w >> 1, wn = w & 1;
  int sl8 = lane & 7;
  const u16* inb = L.inT + (size_t)b * HW * C;

  int px[4], py[4];
  bool pv[4];
  const u16* bbase[4];
#pragma unroll
  for (int i = 0; i < 4; i++) {
    int r = w * 32 + i * 8 + (lane >> 3);
    int p = p0 + r;
    pv[i] = p < HW;
    int pp = pv[i] ? p : 0;
    px[i] = pp % W;
    py[i] = pp / W;
    bbase[i] = inb + (size_t)pp * C + ((sl8 ^ (r & 7)) << 3);
  }
  const u16* awbase[3];
#pragma unroll
  for (int g = 0; g < 3; g++) {
    int row = w * 24 + g * 8 + (lane >> 3);
    awbase[g] = L.wT + (size_t)row * C + ((sl8 ^ (row & 7)) << 3);
  }
  int aoff[2][3], boff[2][4];
#pragma unroll
  for (int ks = 0; ks < 2; ks++) {
    int sl = ks * 4 + (lane >> 4);
#pragma unroll
    for (int mi = 0; mi < 3; mi++) {
      int ar = wm * 48 + mi * 16 + (lane & 15);
      aoff[ks][mi] = ar * 128 + ((sl ^ (ar & 7)) << 4);
    }
#pragma unroll
    for (int ni = 0; ni < 4; ni++) {
      int br = wn * 64 + ni * 16 + (lane & 15);
      boff[ks][ni] = br * 128 + ((sl ^ (br & 7)) << 4);
    }
  }

  f32x4 acc[3][4];
#pragma unroll
  for (int mi = 0; mi < 3; mi++)
#pragma unroll
    for (int ni = 0; ni < 4; ni++) acc[mi][ni] = (f32x4){0.f,0.f,0.f,0.f};

  const int nchunk = C >> 6;
  const int total = 9 * nchunk;

  auto STAGE = [&](int t, int cb, char* buf) {
    int dy = t / 3 - 1, dx = t - (t / 3) * 3 - 1;
    long shift = (long)(dy * W + dx) * C;
    size_t ash = (size_t)t * 96 * C + cb;
#pragma unroll
    for (int g = 0; g < 3; g++) gll16(awbase[g] + ash, buf + (w * 24 + g * 8) * 128);
#pragma unroll
    for (int i = 0; i < 4; i++) {
      int xx = px[i] + dx, yy = py[i] + dy;
      bool ok = pv[i] && ((unsigned)xx < (unsigned)W) && ((unsigned)yy < (unsigned)H);
      const void* src = ok ? (const void*)(bbase[i] + shift + cb) : (const void*)A.zp;
      gll16(src, buf + 12288 + (w * 32 + i * 8) * 128);
    }
  };

  STAGE(0, 0, smem);

  int cur = 0, t = 0, c = 0;
  for (int s = 0; s < total; s++) {
    int tn = t + 1, cn = c;
    if (tn == 9) { tn = 0; cn = c + 1; }
    if (s + 1 < total) {
      STAGE(tn, cn << 6, smem + ((cur ^ 1) * 28672));
      asm volatile("s_waitcnt vmcnt(7)" ::: "memory");
    } else {
      asm volatile("s_waitcnt vmcnt(0)" ::: "memory");
    }
    __builtin_amdgcn_sched_barrier(0);
    __builtin_amdgcn_s_barrier();
    __builtin_amdgcn_sched_barrier(0);

    char* B0 = smem + cur * 28672;
    __builtin_amdgcn_s_setprio(1);
#pragma unroll
    for (int ks = 0; ks < 2; ks++) {
      bf16x8 af[3], bf[4];
#pragma unroll
      for (int mi = 0; mi < 3; mi++) af[mi] = *(const bf16x8*)(B0 + aoff[ks][mi]);
#pragma unroll
      for (int ni = 0; ni < 4; ni++) bf[ni] = *(const bf16x8*)(B0 + 12288 + boff[ks][ni]);
#pragma unroll
      for (int mi = 0; mi < 3; mi++)
#pragma unroll
        for (int ni = 0; ni < 4; ni++)
          acc[mi][ni] = __builtin_amdgcn_mfma_f32_16x16x32_bf16(af[mi], bf[ni], acc[mi][ni], 0, 0, 0);
    }
    __builtin_amdgcn_s_setprio(0);
    __builtin_amdgcn_sched_barrier(0);
    __builtin_amdgcn_s_barrier();
    __builtin_amdgcn_sched_barrier(0);
    cur ^= 1; t = tn; c = cn;
  }

  if (!isReg) {
#pragma unroll
    for (int mi = 0; mi < 3; mi++) {
      int cob = wm * 48 + mi * 16 + ((lane >> 4) << 2);
      if (cob >= 80) continue;
      f32x4 bia = *(const f32x4*)(L.bias + cob);
#pragma unroll
      for (int ni = 0; ni < 4; ni++) {
        int p = p0 + wn * 64 + ni * 16 + (lane & 15);
        if (p >= HW) continue;
#pragma unroll
        for (int j = 0; j < 4; j++)
          A.out[(size_t)(b * 80 + cob + j) * 8400 + L.pos_off + p] = sigm(acc[mi][ni][j] + bia[j]);
      }
    }
  } else {
    float* P = (float*)smem;  // [128][68]
#pragma unroll
    for (int mi = 0; mi < 3; mi++) {
      int cob = wm * 48 + mi * 16 + ((lane >> 4) << 2);
      if (cob < 68) {
        f32x4 bia = *(const f32x4*)(L.bias + cob);
#pragma unroll
        for (int ni = 0; ni < 4; ni++) {
          int n = wn * 64 + ni * 16 + (lane & 15);
          f32x4 v = acc[mi][ni];
#pragma unroll
          for (int j = 0; j < 4; j++) v[j] += bia[j];
          *(f32x4*)(P + n * 68 + cob) = v;
        }
      }
    }
    __syncthreads();
    int n = tid >> 1, g2 = tid & 1;
    int p = p0 + n;
    if (p < HW) {
      float d[2];
#pragma unroll
      for (int gg = 0; gg < 2; gg++) {
        const float* row = P + n * 68 + (g2 * 2 + gg) * 17;
        float mx = row[0];
#pragma unroll
        for (int k = 1; k < 17; k++) mx = fmaxf(mx, row[k]);
        float sum = 0.f, dot = 0.f;
#pragma unroll
        for (int k = 0; k < 17; k++) {
          float e = __expf(row[k] - mx);
          sum += e;
          dot += (float)k * e;
        }
        d[gg] = dot / sum;
      }
      *(float2*)(A.out + RO + ((size_t)b * 8400 + L.pos_off + p) * 4 + g2 * 2) = make_float2(d[0], d[1]);
    }
  }
}

// ---------------- host ----------------
extern "C" void kernel_launch(void* const* d_in, const int* in_sizes, int n_in,
                              void* d_out, int out_size, void* d_ws, size_t ws_size,
                              hipStream_t stream) {
  static const int Cs[3] = {768, 384, 192};
  static const int HWs[3] = {400, 1600, 6400};
  static const int Ws[3] = {20, 40, 80};
  static const int POs[3] = {0, 400, 2000};
  static const long TOFF[3] = {0, 4915200, 14745600};
  static const long WTOFF[3] = {0, 663552, 995328};
  static const long GOFF[3] = {0, 9437184, 11796480};
  static const int NT[3] = {4, 13, 50};
  static const int MB[3] = {12, 6, 3};

  char* wsb = (char*)d_ws;
  u16* zp = (u16*)wsb;
  float* avg = (float*)(wsb + 256);
  float* gc = avg + 3 * BSZ * 768;
  float* gr = gc + 3 * BSZ * 768;
  u16* tcT = (u16*)(gr + 3 * BSZ * 768);
  u16* trT = tcT + 34406400;
  u16* wTc = trT + 34406400;
  u16* wTr = wTc + 1161216;
  u16* featT = wTr + 1161216;
  u16* gwc = featT + 34406400;
  u16* gwr = gwc + 12386304;

  hipMemsetAsync(zp, 0, 256, stream);
  hipMemsetAsync(avg, 0, 3 * BSZ * 768 * sizeof(float), stream);
  hipMemsetAsync(wTc, 0, 2 * 1161216ull * 2, stream);

  for (int l = 0; l < 3; l++) {
    const float* pcw = (const float*)d_in[l * 13 + 9];
    const float* prw = (const float*)d_in[l * 13 + 11];
    hipLaunchKernelGGL(k_wprep, dim3(80 * Cs[l] / 256), dim3(256), 0, stream, pcw, wTc + WTOFF[l], Cs[l]);
    hipLaunchKernelGGL(k_wprep, dim3(68 * Cs[l] / 256), dim3(256), 0, stream, prw, wTr + WTOFF[l], Cs[l]);
  }

  {
    PFArgs PF;
    for (int l = 0; l < 3; l++) {
      PF.feat[l] = (const float*)d_in[l * 13 + 0];
      PF.fT[l] = featT + TOFF[l];
    }
    PF.avg = avg;
    int ps1 = BSZ * 7, ps2 = ps1 + BSZ * 25, ptot = ps2 + BSZ * 100;
    hipLaunchKernelGGL(k_prepF2, dim3(ptot), dim3(256), 0, stream, PF, ps1, ps2);
  }

  {
    GArgs GA;
    for (int l = 0; l < 3; l++) {
      const float* const* p = (const float* const*)(d_in + l * 13);
      GA.cfw[l] = p[1]; GA.cfb[l] = p[2];
      GA.rfw[l] = p[3]; GA.rfb[l] = p[4];
    }
    GA.avg = avg; GA.gc = gc; GA.gr = gr;
    int s1 = BSZ * 768, s2 = s1 + BSZ * 384, tot = s2 + BSZ * 192;
    hipLaunchKernelGGL(k_gate, dim3(tot), dim3(256), 0, stream, GA, s1, s2);
  }

  {
    GWArgs GW;
    for (int l = 0; l < 3; l++) {
      const float* const* p = (const float* const*)(d_in + l * 13);
      GW.w0[l] = p[5];
      GW.w1[l] = p[7];
      GW.goff[l] = GOFF[l];
    }
    GW.gc = gc; GW.gr = gr;
    GW.gwc = gwc; GW.gwr = gwr;
    int g1 = BSZ * 288, g2 = g1 + BSZ * 72, gtot = g2 + BSZ * 18;
    hipLaunchKernelGGL(k_wgate, dim3(gtot), dim3(256), 0, stream, GW, g1, g2);
  }

  {
    C1WArgs C1;
    int bstart = 0;
    for (int l = 0; l < 3; l++) {
      const float* const* p = (const float* const*)(d_in + l * 13);
      C1WLvl& L = C1.l[l];
      L.gwc = gwc + GOFF[l];
      L.gwr = gwr + GOFF[l];
      L.b0 = p[6]; L.b1 = p[8];
      L.fT = featT + TOFF[l];
      L.tcT = tcT + TOFF[l];
      L.trT = trT + TOFF[l];
      L.C = Cs[l]; L.HW = HWs[l]; L.ntiles = NT[l]; L.mblks = MB[l];
      L.bstart = bstart;
      L.cnt = BSZ * NT[l] * MB[l];
      bstart += L.cnt;
    }
    hipLaunchKernelGGL(k_conv1p, dim3(bstart), dim3(256), 0, stream, C1);
  }

  {
    C3MArgs C3;
    int bs3 = 0;
    for (int l = 0; l < 3; l++) {
      const float* const* p = (const float* const*)(d_in + l * 13);
      C3Lvl Lc, Lr;
      Lc.inT = tcT + TOFF[l]; Lc.wT = wTc + WTOFF[l]; Lc.bias = p[10];
      Lr.inT = trT + TOFF[l]; Lr.wT = wTr + WTOFF[l]; Lr.bias = p[12];
      Lc.C = Lr.C = Cs[l]; Lc.W = Lr.W = Ws[l]; Lc.H = Lr.H = Ws[l]; Lc.HW = Lr.HW = HWs[l];
      Lc.ntiles = Lr.ntiles = NT[l];
      Lc.bstart = Lr.bstart = bs3;
      Lc.pos_off = Lr.pos_off = POs[l];
      C3.lc[l] = Lc; C3.lr[l] = Lr;
      bs3 += BSZ * NT[l];
    }
    C3.zp = zp; C3.out = (float*)d_out;
    C3.half = bs3;
    hipLaunchKernelGGL(k_conv3m, dim3(2 * bs3), dim3(256), 0, stream, C3);
  }

  hipLaunchKernelGGL(k_anchor, dim3(33), dim3(256), 0, stream, (float*)d_out);
}

// Round 17
// 384.141 us; speedup vs baseline: 1.3938x; 1.0284x over previous
//
#include <hip/hip_runtime.h>
#include <hip/hip_bf16.h>

typedef __attribute__((ext_vector_type(8))) short bf16x8;
typedef __attribute__((ext_vector_type(4))) float f32x4;
typedef __attribute__((ext_vector_type(4))) unsigned short u16x4;
typedef unsigned short u16;
typedef unsigned int u32;

#define BSZ 16
#define RO 10752000
#define AO 11289600
#define SO 11306400

__device__ __forceinline__ float sigm(float x) { return 1.f / (1.f + __expf(-x)); }

__device__ __forceinline__ u16 f2bf(float f) {
  u32 u = __float_as_uint(f);
  u = u + 0x7FFF + ((u >> 16) & 1);
  return (u16)(u >> 16);
}
__device__ __forceinline__ float bf2f(u16 v) { return __uint_as_float(((u32)v) << 16); }

__device__ __forceinline__ void gll16(const void* g, void* l) {
  __builtin_amdgcn_global_load_lds((const __attribute__((address_space(1))) void*)g,
                                   (__attribute__((address_space(3))) void*)l, 16, 0, 0);
}

// bijective XCD-chunked swizzle (m204) — cost-uniform segments only
__device__ __forceinline__ int xswz(int bid, int n) {
  int q = n >> 3, r = n & 7;
  int x = bid & 7, i = bid >> 3;
  return (x < r ? x * (q + 1) : r * (q + 1) + (x - r) * q) + i;
}

// ---------------- merged: conv3 weight transpose (6 segments) + anchors ----------------
struct WPArgs { const float* w[6]; u16* dst[6]; int C[6]; int bs[6]; int anchor_start; float* out; };

__global__ __launch_bounds__(256) void k_wprepM(WPArgs A) {
  int bid = blockIdx.x;
  if (bid >= A.anchor_start) {
    // anchors
    int g = (bid - A.anchor_start) * 256 + threadIdx.x;
    if (g >= 8400) return;
    int l = g < 400 ? 0 : (g < 2000 ? 1 : 2);
    int off = l == 0 ? 0 : (l == 1 ? 400 : 2000);
    int w = 20 << l;
    float s = (float)(32 >> l);
    int p = g - off;
    int x = p % w, y = p / w;
    A.out[AO + 2 * g] = x + 0.5f;
    A.out[AO + 2 * g + 1] = y + 0.5f;
    A.out[SO + g] = s;
    return;
  }
  int seg = 0;
#pragma unroll
  for (int i = 1; i < 6; i++) if (bid >= A.bs[i]) seg = i;
  int id = (bid - A.bs[seg]) * 256 + threadIdx.x;
  int C = A.C[seg];
  int co = id / C, ci = id - co * C;
  const float* s = A.w[seg] + (size_t)id * 9;
  u16* d = A.dst[seg];
#pragma unroll
  for (int t = 0; t < 9; t++) d[((size_t)(t * 96 + co)) * C + ci] = f2bf(s[t]);
}

// ---------------- featT prep + fused avg partial sums ----------------
struct PFArgs { const float* feat[3]; u16* fT[3]; float* avg; };

__global__ __launch_bounds__(256) void k_prepF2(PFArgs A, int s1, int s2) {
  __shared__ float buf[32][65];
  int bid = blockIdx.x;
  int l = bid >= s2 ? 2 : (bid >= s1 ? 1 : 0);
  int loc = bid - (l == 2 ? s2 : (l == 1 ? s1 : 0));
  int C = 768 >> l, HW = 400 << (2 * l);
  int PT = (HW + 63) / 64;
  int pt = loc % PT, b = loc / PT;
  int p0 = pt * 64;
  int tid = threadIdx.x;
  int cc = tid >> 6, pp = tid & 63;
  int pload = p0 + pp;
  bool lok = pload < HW;
  int plc = lok ? pload : 0;
  int pw = tid >> 2, cg = (tid & 3) * 8;
  bool wok = p0 + pw < HW;
  int rch = tid >> 3, rgp = tid & 7;
  const float* src = A.feat[l] + (size_t)b * C * HW;
  u16* dst = A.fT[l] + (size_t)b * HW * C;
  float* avgb = A.avg + (l * BSZ + b) * 768;
  for (int c0 = 0; c0 < C; c0 += 32) {
#pragma unroll
    for (int j = 0; j < 8; j++) {
      int c = c0 + cc * 8 + j;
      float v = src[(size_t)c * HW + plc];
      buf[cc * 8 + j][pp] = lok ? v : 0.f;
    }
    __syncthreads();
    if (wok) {
      bf16x8 h;
#pragma unroll
      for (int j = 0; j < 8; j++) h[j] = (short)f2bf(buf[cg + j][pw]);
      *(bf16x8*)(dst + (size_t)(p0 + pw) * C + c0 + cg) = h;
    }
    {
      float v = 0.f;
#pragma unroll
      for (int k = 0; k < 8; k++) v += buf[rch][rgp * 8 + k];
      v += __shfl_xor(v, 1);
      v += __shfl_xor(v, 2);
      v += __shfl_xor(v, 4);
      if (rgp == 0) atomicAdd(avgb + c0 + rch, v);
    }
    __syncthreads();
  }
}

// ---------------- gates (avg holds raw sums; fold 1/HW here) ----------------
struct GArgs {
  const float *cfw[3], *cfb[3], *rfw[3], *rfb[3];
  float *avg, *gc, *gr;
};

__global__ __launch_bounds__(256) void k_gate(GArgs A, int s1, int s2) {
  int bid = blockIdx.x;
  int l = bid >= s2 ? 2 : (bid >= s1 ? 1 : 0);
  int loc = bid - (l == 2 ? s2 : (l == 1 ? s1 : 0));
  int C = 768 >> l, HW = 400 << (2 * l);
  float inv = 1.f / (float)HW;
  int co = loc % C, b = loc / C;
  const float* av = A.avg + (l * BSZ + b) * 768;
  float sc = 0.f, sr = 0.f;
  for (int ci = threadIdx.x; ci < C; ci += 256) {
    float v = av[ci];
    sc += A.cfw[l][(size_t)co * C + ci] * v;
    sr += A.rfw[l][(size_t)co * C + ci] * v;
  }
  __shared__ float rc[256], rr[256];
  rc[threadIdx.x] = sc; rr[threadIdx.x] = sr;
  __syncthreads();
  for (int o = 128; o > 0; o >>= 1) {
    if (threadIdx.x < o) { rc[threadIdx.x] += rc[threadIdx.x + o]; rr[threadIdx.x] += rr[threadIdx.x + o]; }
    __syncthreads();
  }
  if (threadIdx.x == 0) {
    A.gc[(l * BSZ + b) * 768 + co] = sigm(rc[0] * inv + A.cfb[l][co]);
    A.gr[(l * BSZ + b) * 768 + co] = sigm(rr[0] * inv + A.rfb[l][co]);
  }
}

// ---------------- gated-weight prep ----------------
struct GWArgs {
  const float *w0[3], *w1[3];
  const float *gc, *gr;
  u16 *gwc, *gwr;
  long goff[3];
};

__global__ __launch_bounds__(256) void k_wgate(GWArgs A, int s1, int s2) {
  int bid = blockIdx.x;
  int l = bid >= s2 ? 2 : (bid >= s1 ? 1 : 0);
  int loc = bid - (l == 2 ? s2 : (l == 1 ? s1 : 0));
  int C = 768 >> l;
  int per_b = (C * C) >> 11;
  int tile = loc % per_b, b = loc / per_b;
  int idx = (tile << 11) + threadIdx.x * 8;
  int co = idx / C, ci = idx - co * C;
  const float* g0 = A.gc + (l * BSZ + b) * 768 + ci;
  const float* g1 = A.gr + (l * BSZ + b) * 768 + ci;
  const float* w0 = A.w0[l] + idx;
  const float* w1 = A.w1[l] + idx;
  f32x4 wa0 = *(const f32x4*)(w0), wb0 = *(const f32x4*)(w0 + 4);
  f32x4 wa1 = *(const f32x4*)(w1), wb1 = *(const f32x4*)(w1 + 4);
  f32x4 ga = *(const f32x4*)(g0), gb = *(const f32x4*)(g0 + 4);
  f32x4 ra = *(const f32x4*)(g1), rb = *(const f32x4*)(g1 + 4);
  bf16x8 h0, h1;
#pragma unroll
  for (int j = 0; j < 4; j++) {
    h0[j] = (short)f2bf(wa0[j] * ga[j]);
    h0[j + 4] = (short)f2bf(wb0[j] * gb[j]);
    h1[j] = (short)f2bf(wa1[j] * ra[j]);
    h1[j + 4] = (short)f2bf(wb1[j] * rb[j]);
  }
  size_t o = A.goff[l] + (size_t)b * C * C + idx;
  *(bf16x8*)(A.gwc + o) = h0;
  *(bf16x8*)(A.gwr + o) = h1;
}

// ---------------- conv1p: dual-branch 1x1 GEMM, counted vmcnt + per-level XCD swizzle + setprio ----------------
struct C1WLvl {
  const u16 *gwc, *gwr;
  const float *b0, *b1;
  const u16* fT;
  u16 *tcT, *trT;
  int C, HW, ntiles, mblks, bstart, cnt;
};
struct C1WArgs { C1WLvl l[3]; };

__global__ __launch_bounds__(256) void k_conv1p(C1WArgs A) {
  __shared__ char smem[65536];
  int bid = blockIdx.x;
  int li = (bid >= A.l[2].bstart) ? 2 : (bid >= A.l[1].bstart ? 1 : 0);
  const C1WLvl& L = A.l[li];
  int loc = xswz(bid - L.bstart, L.cnt);
  int mb = loc % L.mblks;
  int t2 = loc / L.mblks;
  int nt = t2 % L.ntiles;
  int b = t2 / L.ntiles;
  const int C = L.C, HW = L.HW;
  int p0 = nt * 128, co0 = mb * 64;
  int tid = threadIdx.x, lane = tid & 63, w = tid >> 6;
  int wm = w >> 1, wn = w & 1;
  const u16* fTb = L.fT + (size_t)b * HW * C;
  const u16* gw0 = L.gwc + (size_t)b * C * C;
  const u16* gw1 = L.gwr + (size_t)b * C * C;
  int sl8 = lane & 7;

  const u16* bsrc[4];
#pragma unroll
  for (int i = 0; i < 4; i++) {
    int r = w * 32 + i * 8 + (lane >> 3);
    int p = p0 + r;
    if (p >= HW) p = HW - 1;
    bsrc[i] = fTb + (size_t)p * C + ((sl8 ^ (r & 7)) << 3);
  }
  const u16 *a0src[2], *a1src[2];
#pragma unroll
  for (int i = 0; i < 2; i++) {
    int r = w * 16 + i * 8 + (lane >> 3);
    a0src[i] = gw0 + (size_t)(co0 + r) * C + ((sl8 ^ (r & 7)) << 3);
    a1src[i] = gw1 + (size_t)(co0 + r) * C + ((sl8 ^ (r & 7)) << 3);
  }
  int aoff[2][2], boff[2][4];
#pragma unroll
  for (int ks = 0; ks < 2; ks++) {
    int sl = ks * 4 + (lane >> 4);
#pragma unroll
    for (int mi = 0; mi < 2; mi++) {
      int ar = wm * 32 + mi * 16 + (lane & 15);
      aoff[ks][mi] = ar * 128 + ((sl ^ (ar & 7)) << 4);
    }
#pragma unroll
    for (int ni = 0; ni < 4; ni++) {
      int br = wn * 64 + ni * 16 + (lane & 15);
      boff[ks][ni] = br * 128 + ((sl ^ (br & 7)) << 4);
    }
  }

  f32x4 acc0[2][4], acc1[2][4];
#pragma unroll
  for (int mi = 0; mi < 2; mi++)
#pragma unroll
    for (int ni = 0; ni < 4; ni++) { acc0[mi][ni] = (f32x4){0.f,0.f,0.f,0.f}; acc1[mi][ni] = (f32x4){0.f,0.f,0.f,0.f}; }

  const int nchunk = C >> 6;
  {
    char* buf = smem;
#pragma unroll
    for (int i = 0; i < 4; i++) gll16(bsrc[i], buf + 16384 + (w * 32 + i * 8) * 128);
#pragma unroll
    for (int i = 0; i < 2; i++) {
      gll16(a0src[i], buf + (w * 16 + i * 8) * 128);
      gll16(a1src[i], buf + 8192 + (w * 16 + i * 8) * 128);
    }
  }

  int cur = 0;
  for (int c = 0; c < nchunk; c++) {
    if (c + 1 < nchunk) {
      int cb = (c + 1) << 6;
      char* buf = smem + ((cur ^ 1) << 15);
#pragma unroll
      for (int i = 0; i < 4; i++) gll16(bsrc[i] + cb, buf + 16384 + (w * 32 + i * 8) * 128);
#pragma unroll
      for (int i = 0; i < 2; i++) {
        gll16(a0src[i] + cb, buf + (w * 16 + i * 8) * 128);
        gll16(a1src[i] + cb, buf + 8192 + (w * 16 + i * 8) * 128);
      }
      asm volatile("s_waitcnt vmcnt(8)" ::: "memory");
    } else {
      asm volatile("s_waitcnt vmcnt(0)" ::: "memory");
    }
    __builtin_amdgcn_sched_barrier(0);
    __builtin_amdgcn_s_barrier();
    __builtin_amdgcn_sched_barrier(0);

    char* B0 = smem + (cur << 15);
    __builtin_amdgcn_s_setprio(1);
#pragma unroll
    for (int ks = 0; ks < 2; ks++) {
      bf16x8 a0[2], a1[2], bf[4];
#pragma unroll
      for (int mi = 0; mi < 2; mi++) {
        a0[mi] = *(const bf16x8*)(B0 + aoff[ks][mi]);
        a1[mi] = *(const bf16x8*)(B0 + 8192 + aoff[ks][mi]);
      }
#pragma unroll
      for (int ni = 0; ni < 4; ni++) bf[ni] = *(const bf16x8*)(B0 + 16384 + boff[ks][ni]);
#pragma unroll
      for (int mi = 0; mi < 2; mi++)
#pragma unroll
        for (int ni = 0; ni < 4; ni++) {
          acc0[mi][ni] = __builtin_amdgcn_mfma_f32_16x16x32_bf16(a0[mi], bf[ni], acc0[mi][ni], 0, 0, 0);
          acc1[mi][ni] = __builtin_amdgcn_mfma_f32_16x16x32_bf16(a1[mi], bf[ni], acc1[mi][ni], 0, 0, 0);
        }
    }
    __builtin_amdgcn_s_setprio(0);
    __builtin_amdgcn_sched_barrier(0);
    __builtin_amdgcn_s_barrier();
    __builtin_amdgcn_sched_barrier(0);
    cur ^= 1;
  }

#pragma unroll
  for (int mi = 0; mi < 2; mi++) {
    int cob = co0 + wm * 32 + mi * 16 + ((lane >> 4) << 2);
    f32x4 bia0 = *(const f32x4*)(L.b0 + cob);
    f32x4 bia1 = *(const f32x4*)(L.b1 + cob);
#pragma unroll
    for (int ni = 0; ni < 4; ni++) {
      int p = p0 + wn * 64 + ni * 16 + (lane & 15);
      if (p >= HW) continue;
      u16x4 res = *(const u16x4*)(fTb + (size_t)p * C + cob);
      u16x4 o0, o1;
#pragma unroll
      for (int j = 0; j < 4; j++) {
        float x0 = acc0[mi][ni][j] + bia0[j];
        o0[j] = f2bf(x0 * sigm(x0) + bf2f(res[j]));
        float x1 = acc1[mi][ni][j] + bia1[j];
        o1[j] = f2bf(x1 * sigm(x1));
      }
      size_t off = ((size_t)b * HW + p) * C + cob;
      *(u16x4*)(L.tcT + off) = o0;
      *(u16x4*)(L.trT + off) = o1;
    }
  }
}

// ---------------- conv3m: cls+reg merged, tap-inner, 2-phase dbuf + counted vmcnt + setprio ----------------
struct C3Lvl {
  const u16* inT;
  const u16* wT;
  const float* bias;
  int C, W, H, HW, ntiles, bstart, pos_off;
};
struct C3MArgs { C3Lvl lc[3]; C3Lvl lr[3]; const u16* zp; float* out; int half; };

__global__ __launch_bounds__(256) void k_conv3m(C3MArgs A) {
  __shared__ char smem[57344];
  int rb = blockIdx.x;
  bool isReg = rb >= A.half;
  int bid = isReg ? rb - A.half : rb;
  const C3Lvl* lv = isReg ? A.lr : A.lc;
  int li = (bid >= lv[2].bstart) ? 2 : (bid >= lv[1].bstart ? 1 : 0);
  const C3Lvl& L = lv[li];
  int loc = bid - L.bstart;
  int nt = loc % L.ntiles;
  int b = loc / L.ntiles;
  const int C = L.C, W = L.W, H = L.H, HW = L.HW;
  int p0 = nt * 128;
  int tid = threadIdx.x, lane = tid & 63, w = tid >> 6;
  int wm = w >> 1, wn = w & 1;
  int sl8 = lane & 7;
  const u16* inb = L.inT + (size_t)b * HW * C;

  int px[4], py[4];
  bool pv[4];
  const u16* bbase[4];
#pragma unroll
  for (int i = 0; i < 4; i++) {
    int r = w * 32 + i * 8 + (lane >> 3);
    int p = p0 + r;
    pv[i] = p < HW;
    int pp = pv[i] ? p : 0;
    px[i] = pp % W;
    py[i] = pp / W;
    bbase[i] = inb + (size_t)pp * C + ((sl8 ^ (r & 7)) << 3);
  }
  const u16* awbase[3];
#pragma unroll
  for (int g = 0; g < 3; g++) {
    int row = w * 24 + g * 8 + (lane >> 3);
    awbase[g] = L.wT + (size_t)row * C + ((sl8 ^ (row & 7)) << 3);
  }
  int aoff[2][3], boff[2][4];
#pragma unroll
  for (int ks = 0; ks < 2; ks++) {
    int sl = ks * 4 + (lane >> 4);
#pragma unroll
    for (int mi = 0; mi < 3; mi++) {
      int ar = wm * 48 + mi * 16 + (lane & 15);
      aoff[ks][mi] = ar * 128 + ((sl ^ (ar & 7)) << 4);
    }
#pragma unroll
    for (int ni = 0; ni < 4; ni++) {
      int br = wn * 64 + ni * 16 + (lane & 15);
      boff[ks][ni] = br * 128 + ((sl ^ (br & 7)) << 4);
    }
  }

  f32x4 acc[3][4];
#pragma unroll
  for (int mi = 0; mi < 3; mi++)
#pragma unroll
    for (int ni = 0; ni < 4; ni++) acc[mi][ni] = (f32x4){0.f,0.f,0.f,0.f};

  const int nchunk = C >> 6;
  const int total = 9 * nchunk;

  auto STAGE = [&](int t, int cb, char* buf) {
    int dy = t / 3 - 1, dx = t - (t / 3) * 3 - 1;
    long shift = (long)(dy * W + dx) * C;
    size_t ash = (size_t)t * 96 * C + cb;
#pragma unroll
    for (int g = 0; g < 3; g++) gll16(awbase[g] + ash, buf + (w * 24 + g * 8) * 128);
#pragma unroll
    for (int i = 0; i < 4; i++) {
      int xx = px[i] + dx, yy = py[i] + dy;
      bool ok = pv[i] && ((unsigned)xx < (unsigned)W) && ((unsigned)yy < (unsigned)H);
      const void* src = ok ? (const void*)(bbase[i] + shift + cb) : (const void*)A.zp;
      gll16(src, buf + 12288 + (w * 32 + i * 8) * 128);
    }
  };

  STAGE(0, 0, smem);

  int cur = 0, t = 0, c = 0;
  for (int s = 0; s < total; s++) {
    int tn = t + 1, cn = c;
    if (tn == 9) { tn = 0; cn = c + 1; }
    if (s + 1 < total) {
      STAGE(tn, cn << 6, smem + ((cur ^ 1) * 28672));
      asm volatile("s_waitcnt vmcnt(7)" ::: "memory");
    } else {
      asm volatile("s_waitcnt vmcnt(0)" ::: "memory");
    }
    __builtin_amdgcn_sched_barrier(0);
    __builtin_amdgcn_s_barrier();
    __builtin_amdgcn_sched_barrier(0);

    char* B0 = smem + cur * 28672;
    __builtin_amdgcn_s_setprio(1);
#pragma unroll
    for (int ks = 0; ks < 2; ks++) {
      bf16x8 af[3], bf[4];
#pragma unroll
      for (int mi = 0; mi < 3; mi++) af[mi] = *(const bf16x8*)(B0 + aoff[ks][mi]);
#pragma unroll
      for (int ni = 0; ni < 4; ni++) bf[ni] = *(const bf16x8*)(B0 + 12288 + boff[ks][ni]);
#pragma unroll
      for (int mi = 0; mi < 3; mi++)
#pragma unroll
        for (int ni = 0; ni < 4; ni++)
          acc[mi][ni] = __builtin_amdgcn_mfma_f32_16x16x32_bf16(af[mi], bf[ni], acc[mi][ni], 0, 0, 0);
    }
    __builtin_amdgcn_s_setprio(0);
    __builtin_amdgcn_sched_barrier(0);
    __builtin_amdgcn_s_barrier();
    __builtin_amdgcn_sched_barrier(0);
    cur ^= 1; t = tn; c = cn;
  }

  if (!isReg) {
#pragma unroll
    for (int mi = 0; mi < 3; mi++) {
      int cob = wm * 48 + mi * 16 + ((lane >> 4) << 2);
      if (cob >= 80) continue;
      f32x4 bia = *(const f32x4*)(L.bias + cob);
#pragma unroll
      for (int ni = 0; ni < 4; ni++) {
        int p = p0 + wn * 64 + ni * 16 + (lane & 15);
        if (p >= HW) continue;
#pragma unroll
        for (int j = 0; j < 4; j++)
          A.out[(size_t)(b * 80 + cob + j) * 8400 + L.pos_off + p] = sigm(acc[mi][ni][j] + bia[j]);
      }
    }
  } else {
    float* P = (float*)smem;  // [128][68]
#pragma unroll
    for (int mi = 0; mi < 3; mi++) {
      int cob = wm * 48 + mi * 16 + ((lane >> 4) << 2);
      if (cob < 68) {
        f32x4 bia = *(const f32x4*)(L.bias + cob);
#pragma unroll
        for (int ni = 0; ni < 4; ni++) {
          int n = wn * 64 + ni * 16 + (lane & 15);
          f32x4 v = acc[mi][ni];
#pragma unroll
          for (int j = 0; j < 4; j++) v[j] += bia[j];
          *(f32x4*)(P + n * 68 + cob) = v;
        }
      }
    }
    __syncthreads();
    int n = tid >> 1, g2 = tid & 1;
    int p = p0 + n;
    if (p < HW) {
      float d[2];
#pragma unroll
      for (int gg = 0; gg < 2; gg++) {
        const float* row = P + n * 68 + (g2 * 2 + gg) * 17;
        float mx = row[0];
#pragma unroll
        for (int k = 1; k < 17; k++) mx = fmaxf(mx, row[k]);
        float sum = 0.f, dot = 0.f;
#pragma unroll
        for (int k = 0; k < 17; k++) {
          float e = __expf(row[k] - mx);
          sum += e;
          dot += (float)k * e;
        }
        d[gg] = dot / sum;
      }
      *(float2*)(A.out + RO + ((size_t)b * 8400 + L.pos_off + p) * 4 + g2 * 2) = make_float2(d[0], d[1]);
    }
  }
}

// ---------------- host ----------------
extern "C" void kernel_launch(void* const* d_in, const int* in_sizes, int n_in,
                              void* d_out, int out_size, void* d_ws, size_t ws_size,
                              hipStream_t stream) {
  static const int Cs[3] = {768, 384, 192};
  static const int HWs[3] = {400, 1600, 6400};
  static const int Ws[3] = {20, 40, 80};
  static const int POs[3] = {0, 400, 2000};
  static const long TOFF[3] = {0, 4915200, 14745600};
  static const long WTOFF[3] = {0, 663552, 995328};
  static const long GOFF[3] = {0, 9437184, 11796480};
  static const int NT[3] = {4, 13, 50};
  static const int MB[3] = {12, 6, 3};

  char* wsb = (char*)d_ws;
  u16* zp = (u16*)wsb;
  float* avg = (float*)(wsb + 256);
  float* gc = avg + 3 * BSZ * 768;
  float* gr = gc + 3 * BSZ * 768;
  u16* tcT = (u16*)(gr + 3 * BSZ * 768);
  u16* trT = tcT + 34406400;
  u16* wTc = trT + 34406400;
  u16* wTr = wTc + 1161216;
  u16* featT = wTr + 1161216;
  u16* gwc = featT + 34406400;
  u16* gwr = gwc + 12386304;

  hipMemsetAsync(zp, 0, 256, stream);
  hipMemsetAsync(avg, 0, 3 * BSZ * 768 * sizeof(float), stream);
  hipMemsetAsync(wTc, 0, 2 * 1161216ull * 2, stream);

  {
    WPArgs WP;
    int bs = 0;
    for (int l = 0; l < 3; l++) {
      WP.w[l * 2] = (const float*)d_in[l * 13 + 9];
      WP.dst[l * 2] = wTc + WTOFF[l];
      WP.C[l * 2] = Cs[l];
      WP.bs[l * 2] = bs;
      bs += 80 * Cs[l] / 256;
      WP.w[l * 2 + 1] = (const float*)d_in[l * 13 + 11];
      WP.dst[l * 2 + 1] = wTr + WTOFF[l];
      WP.C[l * 2 + 1] = Cs[l];
      WP.bs[l * 2 + 1] = bs;
      bs += 68 * Cs[l] / 256;
    }
    WP.anchor_start = bs;
    WP.out = (float*)d_out;
    hipLaunchKernelGGL(k_wprepM, dim3(bs + 33), dim3(256), 0, stream, WP);
  }

  {
    PFArgs PF;
    for (int l = 0; l < 3; l++) {
      PF.feat[l] = (const float*)d_in[l * 13 + 0];
      PF.fT[l] = featT + TOFF[l];
    }
    PF.avg = avg;
    int ps1 = BSZ * 7, ps2 = ps1 + BSZ * 25, ptot = ps2 + BSZ * 100;
    hipLaunchKernelGGL(k_prepF2, dim3(ptot), dim3(256), 0, stream, PF, ps1, ps2);
  }

  {
    GArgs GA;
    for (int l = 0; l < 3; l++) {
      const float* const* p = (const float* const*)(d_in + l * 13);
      GA.cfw[l] = p[1]; GA.cfb[l] = p[2];
      GA.rfw[l] = p[3]; GA.rfb[l] = p[4];
    }
    GA.avg = avg; GA.gc = gc; GA.gr = gr;
    int s1 = BSZ * 768, s2 = s1 + BSZ * 384, tot = s2 + BSZ * 192;
    hipLaunchKernelGGL(k_gate, dim3(tot), dim3(256), 0, stream, GA, s1, s2);
  }

  {
    GWArgs GW;
    for (int l = 0; l < 3; l++) {
      const float* const* p = (const float* const*)(d_in + l * 13);
      GW.w0[l] = p[5];
      GW.w1[l] = p[7];
      GW.goff[l] = GOFF[l];
    }
    GW.gc = gc; GW.gr = gr;
    GW.gwc = gwc; GW.gwr = gwr;
    int g1 = BSZ * 288, g2 = g1 + BSZ * 72, gtot = g2 + BSZ * 18;
    hipLaunchKernelGGL(k_wgate, dim3(gtot), dim3(256), 0, stream, GW, g1, g2);
  }

  {
    C1WArgs C1;
    int bstart = 0;
    for (int l = 0; l < 3; l++) {
      const float* const* p = (const float* const*)(d_in + l * 13);
      C1WLvl& L = C1.l[l];
      L.gwc = gwc + GOFF[l];
      L.gwr = gwr + GOFF[l];
      L.b0 = p[6]; L.b1 = p[8];
      L.fT = featT + TOFF[l];
      L.tcT = tcT + TOFF[l];
      L.trT = trT + TOFF[l];
      L.C = Cs[l]; L.HW = HWs[l]; L.ntiles = NT[l]; L.mblks = MB[l];
      L.bstart = bstart;
      L.cnt = BSZ * NT[l] * MB[l];
      bstart += L.cnt;
    }
    hipLaunchKernelGGL(k_conv1p, dim3(bstart), dim3(256), 0, stream, C1);
  }

  {
    C3MArgs C3;
    int bs3 = 0;
    for (int l = 0; l < 3; l++) {
      const float* const* p = (const float* const*)(d_in + l * 13);
      C3Lvl Lc, Lr;
      Lc.inT = tcT + TOFF[l]; Lc.wT = wTc + WTOFF[l]; Lc.bias = p[10];
      Lr.inT = trT + TOFF[l]; Lr.wT = wTr + WTOFF[l]; Lr.bias = p[12];
      Lc.C = Lr.C = Cs[l]; Lc.W = Lr.W = Ws[l]; Lc.H = Lr.H = Ws[l]; Lc.HW = Lr.HW = HWs[l];
      Lc.ntiles = Lr.ntiles = NT[l];
      Lc.bstart = Lr.bstart = bs3;
      Lc.pos_off = Lr.pos_off = POs[l];
      C3.lc[l] = Lc; C3.lr[l] = Lr;
      bs3 += BSZ * NT[l];
    }
    C3.zp = zp; C3.out = (float*)d_out;
    C3.half = bs3;
    hipLaunchKernelGGL(k_conv3m, dim3(2 * bs3), dim3(256), 0, stream, C3);
  }
}